// Round 12
// baseline (153.672 us; speedup 1.0000x reference)
//
#include <hip/hip_runtime.h>
#include <math.h>

#define NW     10
#define DIM    1024
#define QDEPTH 16

typedef __attribute__((ext_vector_type(8))) _Float16 f16x8;
typedef __attribute__((ext_vector_type(4))) _Float16 f16x4;
typedef __attribute__((ext_vector_type(2))) _Float16 f16x2;
typedef __attribute__((ext_vector_type(4))) float    f32x4;

// ---------------- ws layout ----------------
#define WS_GATES 0
#define WS_IPERM 8192
#define WS_INVS  81920
#define WS_XH    (1u << 20)     // 16 MB
#define WS_BIL   (17u << 20)    // 4 MB
// d_out scratch (32 MB, fully overwritten by main gemm):
//   Hcol @0 (4MB) | Blo @4MB (4MB) | Ah @8MB (8MB)

// padded LDS slot: breaks power-of-2 stride bank conflicts
#define SLOT(i) ((i) + ((i) >> 4))

__device__ inline void gate2(const float* __restrict__ g, float2& p0, float2& p1) {
    float m00r = g[0], m00i = g[1], m01r = g[2], m01i = g[3];
    float m10r = g[4], m10i = g[5], m11r = g[6], m11i = g[7];
    float n0x = m00r*p0.x - m00i*p0.y + m01r*p1.x - m01i*p1.y;
    float n0y = m00r*p0.y + m00i*p0.x + m01r*p1.y + m01i*p1.x;
    float n1x = m10r*p0.x - m10i*p0.y + m11r*p1.x - m11i*p1.y;
    float n1y = m10r*p0.y + m10i*p0.x + m11r*p1.y + m11i*p1.x;
    p0 = make_float2(n0x, n0y);
    p1 = make_float2(n1x, n1y);
}

__global__ __launch_bounds__(1024)
void prep_kernel(const float* __restrict__ w, float* __restrict__ gates,
                 int* __restrict__ iperm) {
    int t = threadIdx.x;
    const float PI = 3.14159265358979323846f;
    if (t < QDEPTH * NW) {
        // Rot(phi,theta,omega) = RZ(omega) RY(theta) RZ(phi); angles = tanh(w)*pi
        float phi   = tanhf(w[t*3 + 0]) * PI;
        float theta = tanhf(w[t*3 + 1]) * PI;
        float omega = tanhf(w[t*3 + 2]) * PI;
        float ch = cosf(theta * 0.5f), sh = sinf(theta * 0.5f);
        float ap = (phi + omega) * 0.5f;
        float am = (phi - omega) * 0.5f;
        float* g = gates + t * 8;
        g[0] =  cosf(ap) * ch;  g[1] = -sinf(ap) * ch;   // m00
        g[2] = -cosf(am) * sh;  g[3] = -sinf(am) * sh;   // m01
        g[4] =  cosf(am) * sh;  g[5] = -sinf(am) * sh;   // m10
        g[6] =  cosf(ap) * ch;  g[7] =  sinf(ap) * ch;   // m11
    }
    // Forward CNOT-block gather (round-1 verified): state'[v] = state[G_l(v)]
    int v = t;
    for (int l = 0; l < QDEPTH; ++l) {
        int r = (l % (NW - 1)) + 1;
        int u = v;
        for (int wq = NW - 1; wq >= 0; --wq) {
            int bc = 9 - wq;
            int bt = 9 - ((wq + r) % NW);
            u ^= ((u >> bc) & 1) << bt;
        }
        iperm[l * DIM + v] = u;
    }
}

// Fused kernel: 4096 blocks.
//   bid in [0,1024)    : column v=bid of U_lo (layers 0..7)  -> Blo row v
//   bid in [1024,2048) : column v=bid-1024 of U_hi (layers 8..15) -> Hcol row v
//   bid in [2048,4096) : normcast for batch rows 4*(bid-2048)..+3
// Sim body = round-8 verified structure (hoisted slots, perm fused into the
// b=8 pass gather and into the output write), 8 layers per block.
__global__ __launch_bounds__(256)
void fused_sim_kernel(const float* __restrict__ gates, const int* __restrict__ iperm,
                      _Float16* __restrict__ Blo, _Float16* __restrict__ Hcol,
                      const float* __restrict__ x, _Float16* __restrict__ Xh,
                      float* __restrict__ invs) {
    __shared__ float2 st[DIM + 64];
    const int bid = blockIdx.x;
    const int t   = threadIdx.x;

    if (bid >= 2048) {
        // ---------------- normcast: 4 rows per block, 1 wave per row --------
        const int b = (bid - 2048) * 4 + (t >> 6);
        const int l = t & 63;
        const float4* xr = (const float4*)(x + (size_t)b * DIM);
        float4 v[4];
        float ss = 0.f;
        #pragma unroll
        for (int c = 0; c < 4; ++c) {
            v[c] = xr[l + c * 64];
            ss += v[c].x*v[c].x + v[c].y*v[c].y + v[c].z*v[c].z + v[c].w*v[c].w;
        }
        #pragma unroll
        for (int o = 32; o >= 1; o >>= 1) ss += __shfl_down(ss, o, 64);
        ss = __shfl(ss, 0, 64);
        if (l == 0) invs[b] = 1024.0f / ss;
        f16x4* xo = (f16x4*)(Xh + (size_t)b * DIM);
        #pragma unroll
        for (int c = 0; c < 4; ++c) {
            f16x4 h;
            h[0] = (_Float16)v[c].x; h[1] = (_Float16)v[c].y;
            h[2] = (_Float16)v[c].z; h[3] = (_Float16)v[c].w;
            xo[l + c * 64] = h;
        }
        return;
    }

    // ---------------- half-circuit column sim ----------------
    const int half = bid >> 10;          // 0 = U_lo, 1 = U_hi
    const int v    = bid & 1023;
    const int lb   = half ? 8 : 0;       // layer base

    // hoisted layer-invariant slot indices
    int s4[4];
    #pragma unroll
    for (int k = 0; k < 4; ++k) s4[k] = SLOT(t + k * 256);
    int sq[4][4];
    #pragma unroll
    for (int pp = 0; pp < 4; ++pp) {
        const int b = 2 * pp;
        const int low = t & ((1 << b) - 1);
        const int i00 = ((t >> b) << (b + 2)) | low;
        sq[pp][0] = SLOT(i00);
        sq[pp][1] = SLOT(i00 | (1 << b));
        sq[pp][2] = SLOT(i00 | (2 << b));
        sq[pp][3] = SLOT(i00 | (3 << b));
    }

    #pragma unroll
    for (int k = 0; k < 4; ++k) {
        int i = t + k * 256;
        st[s4[k]] = make_float2(i == v ? 1.f : 0.f, 0.f);
    }
    __syncthreads();

    for (int l = lb; l < lb + 8; ++l) {
        const float* gl = gates + l * NW * 8;

        // ---- pass b=8 (wires 0,1) with fused gather of perm l-1 ----
        float2 a00, a01, a10, a11;
        if (l == lb) {
            a00 = st[s4[0]]; a01 = st[s4[1]]; a10 = st[s4[2]]; a11 = st[s4[3]];
        } else {
            const int* ipm = iperm + (l - 1) * DIM;
            int g0 = ipm[t], g1 = ipm[t + 256], g2 = ipm[t + 512], g3 = ipm[t + 768];
            a00 = st[SLOT(g0)]; a01 = st[SLOT(g1)];
            a10 = st[SLOT(g2)]; a11 = st[SLOT(g3)];
        }
        gate2(gl + 0, a00, a10);   // wire 0 (bit 9)
        gate2(gl + 0, a01, a11);
        gate2(gl + 8, a00, a01);   // wire 1 (bit 8)
        gate2(gl + 8, a10, a11);
        if (l != lb) __syncthreads();   // drain gathers before canonical writes
        st[s4[0]] = a00; st[s4[1]] = a01; st[s4[2]] = a10; st[s4[3]] = a11;
        __syncthreads();

        // ---- passes b = 6,4,2,0: thread-exclusive quads ----
        #pragma unroll
        for (int pp = 3; pp >= 0; --pp) {
            const int b = 2 * pp;
            const float* gh = gl + (8 - b) * 8;   // gate on bit b+1 (wire 8-b)
            const float* gm = gl + (9 - b) * 8;   // gate on bit b   (wire 9-b)
            float2 c00 = st[sq[pp][0]], c01 = st[sq[pp][1]];
            float2 c10 = st[sq[pp][2]], c11 = st[sq[pp][3]];
            gate2(gh, c00, c10);
            gate2(gh, c01, c11);
            gate2(gm, c00, c01);
            gate2(gm, c10, c11);
            st[sq[pp][0]] = c00; st[sq[pp][1]] = c01;
            st[sq[pp][2]] = c10; st[sq[pp][3]] = c11;
            __syncthreads();
        }
    }

    // ---- output with fused final perm G_{lb+7} ----
    const int* ipl = iperm + (lb + 7) * DIM;
    if (half == 0) {
        // Blo row v: [i] = Re (U_lo e_v)_i, [1024+i] = Im
        _Float16* row = Blo + (size_t)v * 2048;
        #pragma unroll
        for (int k = 0; k < 4; ++k) {
            int i = t + k * 256;
            float2 a = st[SLOT(ipl[i])];
            row[i]        = (_Float16)a.x;
            row[1024 + i] = (_Float16)a.y;
        }
    } else {
        // Hcol row v: [2i] = Re (U_hi e_v)_i, [2i+1] = Im
        _Float16* col = Hcol + (size_t)v * 2048;
        #pragma unroll
        for (int k = 0; k < 4; ++k) {
            int i = t + k * 256;
            float2 a = st[SLOT(ipl[i])];
            f16x2 p;
            p[0] = (_Float16)a.x;
            p[1] = (_Float16)a.y;
            *(f16x2*)(col + 2 * i) = p;
        }
    }
}

// Expand Hcol (1024 x 2048: row c = column c of U_hi, Re/Im interleaved) into
// A_h (2048 x 2048): A[2j] = (ReH[j,:], -ImH[j,:]); A[2j+1] = (ImH[j,:], ReH[j,:]).
__global__ __launch_bounds__(256)
void expand_kernel(const _Float16* __restrict__ Hcol, _Float16* __restrict__ Ah) {
    __shared__ _Float16 tile[64][130];   // 130: odd dword stride -> conflict-free cols
    const int kb = blockIdx.x * 64;      // k' tile (columns of H)
    const int jb = blockIdx.y * 64;      // j tile (rows of H)
    const int t  = threadIdx.x;

    // load 64 Hcol rows x 128 f16 (j-pairs 2*jb .. 2*jb+127), coalesced
    {
        const int r = t >> 2;            // 0..63
        const int c = (t & 3) * 32;      // 0,32,64,96
        #pragma unroll
        for (int u = 0; u < 4; ++u) {
            *(f16x8*)&tile[r][c + u * 8] =
                *(const f16x8*)(Hcol + (size_t)(kb + r) * 2048 + 2 * jb + c + u * 8);
        }
    }
    __syncthreads();

    const int qp = (t & 31) * 2;         // k' pair within tile
    const int j0 = t >> 5;               // 0..7
    #pragma unroll
    for (int u = 0; u < 8; ++u) {
        const int jj = j0 + u * 8;       // 0..63
        _Float16 re0 = tile[qp][2 * jj],     re1 = tile[qp + 1][2 * jj];
        _Float16 im0 = tile[qp][2 * jj + 1], im1 = tile[qp + 1][2 * jj + 1];
        const size_t r0 = (size_t)(2 * (jb + jj)) * 2048;
        const size_t r1 = r0 + 2048;
        f16x2 a, b, c, d;
        a[0] = re0;  a[1] = re1;     // A[2j][k']      =  Re
        b[0] = -im0; b[1] = -im1;    // A[2j][1024+k'] = -Im
        c[0] = im0;  c[1] = im1;     // A[2j+1][k']    =  Im
        d[0] = re0;  d[1] = re1;     // A[2j+1][1024+k'] = Re
        *(f16x2*)(Ah + r0 + kb + qp)        = a;
        *(f16x2*)(Ah + r0 + 1024 + kb + qp) = b;
        *(f16x2*)(Ah + r1 + kb + qp)        = c;
        *(f16x2*)(Ah + r1 + 1024 + kb + qp) = d;
    }
}

// f16x8 frag read from a [rows][64] half-slot with chunk-XOR swizzle
__device__ __forceinline__ f16x8 ldsfrag(const _Float16* base, int hrow, int c) {
    return *(const f16x8*)(base + hrow * 64 + ((c ^ (hrow & 7)) << 3));
}

// Combine GEMM: Bil[n][k] = sum_{k'} Ah[n][k'] * Blo[k][k'].
// M=2048, N=1024, K=2048. 128x64 tile, BK=64, 4 waves (2x2), double-buffered.
#define CBM 128
#define CBN 64
#define CBK 64
#define CKS 32    // 2048/64

__global__ __launch_bounds__(256)
void combine_kernel(const _Float16* __restrict__ Ah, const _Float16* __restrict__ Blo,
                    _Float16* __restrict__ Bil) {
    __shared__ _Float16 As[2][CBM * CBK];   // 2 x 16 KB
    __shared__ _Float16 Bs[2][CBN * CBK];   // 2 x  8 KB
    const int t = threadIdx.x, lane = t & 63, wid = t >> 6;
    const int wm = wid >> 1, wn = wid & 1;  // wave tile 64x32
    const int m0 = blockIdx.y * CBM;
    const int n0 = blockIdx.x * CBN;
    const int fr = lane & 15;
    const int ch = lane >> 4;

    #define CSTAGE(buf, kt)                                                         \
        do {                                                                        \
            _Pragma("unroll")                                                       \
            for (int u = 0; u < 4; ++u) {                                           \
                const int chn = t + 256 * u;                                        \
                const int row = chn >> 3, cp = chn & 7;                             \
                __builtin_amdgcn_global_load_lds(                                   \
                    (const __attribute__((address_space(1))) void*)                 \
                        (Ah + (size_t)(m0 + row) * 2048 + (kt) * CBK                \
                            + ((cp ^ (row & 7)) << 3)),                             \
                    (__attribute__((address_space(3))) void*)(&As[buf][chn * 8]),   \
                    16, 0, 0);                                                      \
            }                                                                       \
            _Pragma("unroll")                                                       \
            for (int u = 0; u < 2; ++u) {                                           \
                const int chn = t + 256 * u;                                        \
                const int row = chn >> 3, cp = chn & 7;                             \
                __builtin_amdgcn_global_load_lds(                                   \
                    (const __attribute__((address_space(1))) void*)                 \
                        (Blo + (size_t)(n0 + row) * 2048 + (kt) * CBK               \
                            + ((cp ^ (row & 7)) << 3)),                             \
                    (__attribute__((address_space(3))) void*)(&Bs[buf][chn * 8]),   \
                    16, 0, 0);                                                      \
            }                                                                       \
        } while (0)

    f32x4 acc[4][2];
    const f32x4 zero = {0.f, 0.f, 0.f, 0.f};
    #pragma unroll
    for (int i = 0; i < 4; ++i)
        #pragma unroll
        for (int j = 0; j < 2; ++j) acc[i][j] = zero;

    CSTAGE(0, 0);
    __syncthreads();

    for (int s = 0; s < CKS; ++s) {
        const int buf = s & 1;
        if (s + 1 < CKS) CSTAGE(buf ^ 1, s + 1);

        const _Float16* Ab = As[buf];
        const _Float16* Bb = Bs[buf];
        f16x8 af[4][2], bf[2][2];
        #pragma unroll
        for (int mf = 0; mf < 4; ++mf)
            #pragma unroll
            for (int ks = 0; ks < 2; ++ks)
                af[mf][ks] = ldsfrag(Ab, wm * 64 + mf * 16 + fr, ks * 4 + ch);
        #pragma unroll
        for (int nf = 0; nf < 2; ++nf)
            #pragma unroll
            for (int ks = 0; ks < 2; ++ks)
                bf[nf][ks] = ldsfrag(Bb, wn * 32 + nf * 16 + fr, ks * 4 + ch);
        #pragma unroll
        for (int mf = 0; mf < 4; ++mf)
            #pragma unroll
            for (int nf = 0; nf < 2; ++nf)
                #pragma unroll
                for (int ks = 0; ks < 2; ++ks)
                    acc[mf][nf] = __builtin_amdgcn_mfma_f32_16x16x32_f16(
                        af[mf][ks], bf[nf][ks], acc[mf][nf], 0, 0, 0);

        __syncthreads();   // drains vmcnt(0): next buffer staged; reads done
    }
    #undef CSTAGE

    const int colf = lane & 15;
    const int rowf = (lane >> 4) * 4;
    #pragma unroll
    for (int mf = 0; mf < 4; ++mf) {
        #pragma unroll
        for (int nf = 0; nf < 2; ++nf) {
            const int col = n0 + wn * 32 + nf * 16 + colf;
            #pragma unroll
            for (int r = 0; r < 4; ++r) {
                const int row = m0 + wm * 64 + mf * 16 + rowf + r;
                Bil[(size_t)row * 1024 + col] = (_Float16)acc[mf][nf][r];
            }
        }
    }
}

// ---------------- Main GEMM: 256x256 tile, BK=64, 8-phase (round-7, verified)
#define GBK 64
#define NKT 16     // 1024 / 64

__global__ __launch_bounds__(512, 2)
void gemm_kernel(const _Float16* __restrict__ A, const _Float16* __restrict__ B,
                 const float* __restrict__ invs, float* __restrict__ out) {
    __shared__ _Float16 As[2][2][8192];   // [buf][M-half][128 rows x 64 k], 64 KB
    __shared__ _Float16 Bs[2][2][8192];   // [buf][N-half][...], 64 KB
    const int t    = threadIdx.x;
    const int lane = t & 63;
    const int wid  = t >> 6;      // 0..7
    const int wm   = wid >> 2;    // 0..1 : M-half (128 rows)
    const int wn   = wid & 3;     // 0..3 : N-quarter (64 cols)

    // T1: XCD x gets m-panels 4x..4x+3, all 8 n-panels
    const int bid   = blockIdx.x;          // 256 blocks
    const int local = bid >> 3;            // 0..31
    const int m0 = ((bid & 7) * 4 + (local & 3)) * 256;
    const int n0 = (local >> 2) * 256;

    const _Float16* Ag0 = A + (size_t)m0 * 1024;          // A-half0 (rows m0..+127)
    const _Float16* Ag1 = A + (size_t)(m0 + 128) * 1024;  // A-half1
    const _Float16* Bg0 = B + (size_t)n0 * 1024;
    const _Float16* Bg1 = B + (size_t)(n0 + 128) * 1024;

    const int srow = t >> 3;                       // 0..63 (and +64)
    const int sgc  = ((t & 7) ^ (srow & 7)) * 8;   // swizzled source chunk, elems
    #define STAGE_HALF(dst, gbase, kt)                                              \
        do {                                                                        \
            __builtin_amdgcn_global_load_lds(                                       \
                (const __attribute__((address_space(1))) void*)                     \
                    ((gbase) + (size_t)srow * 1024 + (kt) * 64 + sgc),              \
                (__attribute__((address_space(3))) void*)((dst) + t * 8), 16, 0, 0);\
            __builtin_amdgcn_global_load_lds(                                       \
                (const __attribute__((address_space(1))) void*)                     \
                    ((gbase) + (size_t)(64 + srow) * 1024 + (kt) * 64 + sgc),       \
                (__attribute__((address_space(3))) void*)((dst) + 4096 + t * 8),    \
                16, 0, 0);                                                          \
        } while (0)

    f32x4 acc[8][4];
    const f32x4 zero = {0.f, 0.f, 0.f, 0.f};
    #pragma unroll
    for (int i = 0; i < 8; ++i)
        #pragma unroll
        for (int j = 0; j < 4; ++j) acc[i][j] = zero;

    const int fr = lane & 15;       // frag row within 16
    const int ch = lane >> 4;       // 16B chunk within 32-k sub-tile

    // ---- prologue: tile 0 fully + A-half0 of tile 1; wait tile 0 only ----
    STAGE_HALF(&As[0][0][0], Ag0, 0);
    STAGE_HALF(&As[0][1][0], Ag1, 0);
    STAGE_HALF(&Bs[0][0][0], Bg0, 0);
    STAGE_HALF(&Bs[0][1][0], Bg1, 0);
    STAGE_HALF(&As[1][0][0], Ag0, 1);
    asm volatile("s_waitcnt vmcnt(2)" ::: "memory");
    __builtin_amdgcn_s_barrier();
    __builtin_amdgcn_sched_barrier(0);

    for (int tk = 0; tk < NKT; ++tk) {
        const int buf = tk & 1, nbuf = buf ^ 1;
        const _Float16* Ab = &As[buf][wm][0];
        const _Float16* Bb = &Bs[buf][wn >> 1][0];
        const int bro = (wn & 1) * 64;            // B hrow offset within half

        f16x8 afl[4][2], afh[4][2], bfa[2][2], bfb[2][2];

        // ---- phase 0: read afl + bfa; stage A-half1(t+1) ----
        #pragma unroll
        for (int m = 0; m < 4; ++m)
            #pragma unroll
            for (int ks = 0; ks < 2; ++ks)
                afl[m][ks] = ldsfrag(Ab, m * 16 + fr, ks * 4 + ch);
        #pragma unroll
        for (int n = 0; n < 2; ++n)
            #pragma unroll
            for (int ks = 0; ks < 2; ++ks)
                bfa[n][ks] = ldsfrag(Bb, bro + n * 16 + fr, ks * 4 + ch);
        if (tk + 1 < NKT) STAGE_HALF(&As[nbuf][1][0], Ag1, tk + 1);
        __builtin_amdgcn_s_barrier();
        asm volatile("s_waitcnt lgkmcnt(0)" ::: "memory");
        __builtin_amdgcn_sched_barrier(0);
        __builtin_amdgcn_s_setprio(1);
        #pragma unroll
        for (int m = 0; m < 4; ++m)
            #pragma unroll
            for (int n = 0; n < 2; ++n)
                #pragma unroll
                for (int ks = 0; ks < 2; ++ks)
                    acc[m][n] = __builtin_amdgcn_mfma_f32_16x16x32_f16(
                        afl[m][ks], bfa[n][ks], acc[m][n], 0, 0, 0);
        __builtin_amdgcn_s_setprio(0);
        __builtin_amdgcn_s_barrier();
        __builtin_amdgcn_sched_barrier(0);

        // ---- phase 1: read bfb; stage B-half0(t+1) ----
        #pragma unroll
        for (int n = 0; n < 2; ++n)
            #pragma unroll
            for (int ks = 0; ks < 2; ++ks)
                bfb[n][ks] = ldsfrag(Bb, bro + (2 + n) * 16 + fr, ks * 4 + ch);
        if (tk + 1 < NKT) STAGE_HALF(&Bs[nbuf][0][0], Bg0, tk + 1);
        __builtin_amdgcn_s_barrier();
        asm volatile("s_waitcnt lgkmcnt(0)" ::: "memory");
        __builtin_amdgcn_sched_barrier(0);
        __builtin_amdgcn_s_setprio(1);
        #pragma unroll
        for (int m = 0; m < 4; ++m)
            #pragma unroll
            for (int n = 0; n < 2; ++n)
                #pragma unroll
                for (int ks = 0; ks < 2; ++ks)
                    acc[m][2 + n] = __builtin_amdgcn_mfma_f32_16x16x32_f16(
                        afl[m][ks], bfb[n][ks], acc[m][2 + n], 0, 0, 0);
        __builtin_amdgcn_s_setprio(0);
        __builtin_amdgcn_s_barrier();
        __builtin_amdgcn_sched_barrier(0);

        // ---- phase 2: read afh; stage B-half1(t+1) ----
        #pragma unroll
        for (int m = 0; m < 4; ++m)
            #pragma unroll
            for (int ks = 0; ks < 2; ++ks)
                afh[m][ks] = ldsfrag(Ab, 64 + m * 16 + fr, ks * 4 + ch);
        if (tk + 1 < NKT) STAGE_HALF(&Bs[nbuf][1][0], Bg1, tk + 1);
        __builtin_amdgcn_s_barrier();
        asm volatile("s_waitcnt lgkmcnt(0)" ::: "memory");
        __builtin_amdgcn_sched_barrier(0);
        __builtin_amdgcn_s_setprio(1);
        #pragma unroll
        for (int m = 0; m < 4; ++m)
            #pragma unroll
            for (int n = 0; n < 2; ++n)
                #pragma unroll
                for (int ks = 0; ks < 2; ++ks)
                    acc[4 + m][n] = __builtin_amdgcn_mfma_f32_16x16x32_f16(
                        afh[m][ks], bfa[n][ks], acc[4 + m][n], 0, 0, 0);
        __builtin_amdgcn_s_setprio(0);
        __builtin_amdgcn_s_barrier();
        __builtin_amdgcn_sched_barrier(0);

        // ---- phase 3: stage A-half0(t+2) into As[buf][0] (dead since p2) ----
        if (tk + 2 < NKT) STAGE_HALF(&As[buf][0][0], Ag0, tk + 2);
        __builtin_amdgcn_s_barrier();
        asm volatile("s_waitcnt lgkmcnt(0)" ::: "memory");
        __builtin_amdgcn_sched_barrier(0);
        __builtin_amdgcn_s_setprio(1);
        #pragma unroll
        for (int m = 0; m < 4; ++m)
            #pragma unroll
            for (int n = 0; n < 2; ++n)
                #pragma unroll
                for (int ks = 0; ks < 2; ++ks)
                    acc[4 + m][2 + n] = __builtin_amdgcn_mfma_f32_16x16x32_f16(
                        afh[m][ks], bfb[n][ks], acc[4 + m][2 + n], 0, 0, 0);
        __builtin_amdgcn_s_setprio(0);
        // boundary: tile t+1 ready when only A0(t+2)'s 2 loads remain in flight
        if (tk + 1 < NKT) {
            if (tk + 2 < NKT) asm volatile("s_waitcnt vmcnt(2)" ::: "memory");
            else              asm volatile("s_waitcnt vmcnt(0)" ::: "memory");
            __builtin_amdgcn_s_barrier();
            __builtin_amdgcn_sched_barrier(0);
        }
    }
    #undef STAGE_HALF

    // epilogue: C row = m0+wm*128+mf*16+(lane>>4)*4+r ; col = n0+wn*64+nf*16+(lane&15)
    const int colf = lane & 15;
    const int rowf = (lane >> 4) * 4;
    #pragma unroll
    for (int mf = 0; mf < 8; ++mf) {
        #pragma unroll
        for (int nf = 0; nf < 4; ++nf) {
            const int n = n0 + wn * 64 + nf * 16 + colf;
            #pragma unroll
            for (int r = 0; r < 4; ++r) {
                const int row = m0 + wm * 128 + mf * 16 + rowf + r;
                float vv = acc[mf][nf][r];
                float sq = vv * vv;
                float other = __shfl_xor(sq, 1, 64);
                if (!(lane & 1)) {
                    float p = fminf((sq + other) * invs[row], 1.0f);
                    out[(size_t)row * DIM + (n >> 1)] = p;
                }
            }
        }
    }
}

extern "C" void kernel_launch(void* const* d_in, const int* in_sizes, int n_in,
                              void* d_out, int out_size, void* d_ws, size_t ws_size,
                              hipStream_t stream) {
    const float* x = (const float*)d_in[0];     // (8192,1,32,32) fp32
    const float* w = (const float*)d_in[1];     // (16,10,3) fp32
    float* out = (float*)d_out;                 // (8192,1,32,32) fp32

    char* ws = (char*)d_ws;
    float*     gates = (float*)(ws + WS_GATES);
    int*       iperm = (int*)(ws + WS_IPERM);
    float*     invs  = (float*)(ws + WS_INVS);
    _Float16*  Xh    = (_Float16*)(ws + WS_XH);
    _Float16*  Bil   = (_Float16*)(ws + WS_BIL);
    // d_out scratch: Hcol(4MB) | Blo(4MB) | Ah(8MB) — all consumed by
    // combine/expand before the main gemm rewrites every element of d_out.
    char* ob = (char*)d_out;
    _Float16*  Hcol = (_Float16*)(ob);
    _Float16*  Blo  = (_Float16*)(ob + (4u << 20));
    _Float16*  Ah   = (_Float16*)(ob + (8u << 20));

    prep_kernel<<<1, 1024, 0, stream>>>(w, gates, iperm);
    fused_sim_kernel<<<4096, 256, 0, stream>>>(gates, iperm, Blo, Hcol, x, Xh, invs);
    expand_kernel<<<dim3(16, 16), 256, 0, stream>>>(Hcol, Ah);
    combine_kernel<<<dim3(16, 16), 256, 0, stream>>>(Ah, Blo, Bil);
    gemm_kernel<<<256, 512, 0, stream>>>(Xh, Bil, invs, out);
}

// Round 13
// 113.789 us; speedup vs baseline: 1.3505x; 1.3505x over previous
//
#include <hip/hip_runtime.h>
#include <math.h>

#define NW     10
#define DIM    1024
#define QDEPTH 16

typedef __attribute__((ext_vector_type(8))) _Float16 f16x8;
typedef __attribute__((ext_vector_type(4))) _Float16 f16x4;
typedef __attribute__((ext_vector_type(2))) _Float16 f16x2;
typedef __attribute__((ext_vector_type(4))) float    f32x4;

// ---------------- ws layout ----------------
#define WS_GATES 0
#define WS_IPERM 8192
#define WS_INVS  81920
#define WS_XH    (1u << 20)     // 16 MB
#define WS_BIL   (17u << 20)    // 4 MB  (rows 0..1023 = Re U, 1024..2047 = Im U)
// d_out scratch: Ucol @0 (4 MB), consumed by transpose before gemm overwrites.

// padded LDS slot: breaks power-of-2 stride bank conflicts
#define SLOT(i) ((i) + ((i) >> 4))

__device__ inline void gate2(const float* __restrict__ g, float2& p0, float2& p1) {
    float m00r = g[0], m00i = g[1], m01r = g[2], m01i = g[3];
    float m10r = g[4], m10i = g[5], m11r = g[6], m11i = g[7];
    float n0x = m00r*p0.x - m00i*p0.y + m01r*p1.x - m01i*p1.y;
    float n0y = m00r*p0.y + m00i*p0.x + m01r*p1.y + m01i*p1.x;
    float n1x = m10r*p0.x - m10i*p0.y + m11r*p1.x - m11i*p1.y;
    float n1y = m10r*p0.y + m10i*p0.x + m11r*p1.y + m11i*p1.x;
    p0 = make_float2(n0x, n0y);
    p1 = make_float2(n1x, n1y);
}

__global__ __launch_bounds__(1024)
void prep_kernel(const float* __restrict__ w, float* __restrict__ gates,
                 int* __restrict__ iperm) {
    int t = threadIdx.x;
    const float PI = 3.14159265358979323846f;
    if (t < QDEPTH * NW) {
        // Rot(phi,theta,omega) = RZ(omega) RY(theta) RZ(phi); angles = tanh(w)*pi
        float phi   = tanhf(w[t*3 + 0]) * PI;
        float theta = tanhf(w[t*3 + 1]) * PI;
        float omega = tanhf(w[t*3 + 2]) * PI;
        float ch = cosf(theta * 0.5f), sh = sinf(theta * 0.5f);
        float ap = (phi + omega) * 0.5f;
        float am = (phi - omega) * 0.5f;
        float* g = gates + t * 8;
        g[0] =  cosf(ap) * ch;  g[1] = -sinf(ap) * ch;   // m00
        g[2] = -cosf(am) * sh;  g[3] = -sinf(am) * sh;   // m01
        g[4] =  cosf(am) * sh;  g[5] = -sinf(am) * sh;   // m10
        g[6] =  cosf(ap) * ch;  g[7] =  sinf(ap) * ch;   // m11
    }
    // Forward CNOT-block gather (round-1 verified): state'[v] = state[G_l(v)]
    int v = t;
    for (int l = 0; l < QDEPTH; ++l) {
        int r = (l % (NW - 1)) + 1;
        int u = v;
        for (int wq = NW - 1; wq >= 0; --wq) {
            int bc = 9 - wq;
            int bt = 9 - ((wq + r) % NW);
            u ^= ((u >> bc) & 1) << bt;
        }
        iperm[l * DIM + v] = u;
    }
}

// Fused: 3072 blocks.
//   bid < 1024        : round-8 verified 16-layer column sim -> Ucol row bid
//   bid in [1024,3072): normcast for batch rows 4*(bid-1024)..+3
// Normcast blocks fill the wave slots the 1024 sim blocks leave idle.
__global__ __launch_bounds__(256)
void fused_sim_kernel(const float* __restrict__ gates, const int* __restrict__ iperm,
                      _Float16* __restrict__ Ucol,
                      const float* __restrict__ x, _Float16* __restrict__ Xh,
                      float* __restrict__ invs) {
    __shared__ float2 st[DIM + 64];
    const int bid = blockIdx.x;
    const int t   = threadIdx.x;

    if (bid >= 1024) {
        // ---------------- normcast: 4 rows per block, 1 wave per row --------
        const int b = (bid - 1024) * 4 + (t >> 6);
        const int l = t & 63;
        const float4* xr = (const float4*)(x + (size_t)b * DIM);
        float4 v[4];
        float ss = 0.f;
        #pragma unroll
        for (int c = 0; c < 4; ++c) {
            v[c] = xr[l + c * 64];
            ss += v[c].x*v[c].x + v[c].y*v[c].y + v[c].z*v[c].z + v[c].w*v[c].w;
        }
        #pragma unroll
        for (int o = 32; o >= 1; o >>= 1) ss += __shfl_down(ss, o, 64);
        ss = __shfl(ss, 0, 64);
        if (l == 0) invs[b] = 1024.0f / ss;
        f16x4* xo = (f16x4*)(Xh + (size_t)b * DIM);
        #pragma unroll
        for (int c = 0; c < 4; ++c) {
            f16x4 h;
            h[0] = (_Float16)v[c].x; h[1] = (_Float16)v[c].y;
            h[2] = (_Float16)v[c].z; h[3] = (_Float16)v[c].w;
            xo[l + c * 64] = h;
        }
        return;
    }

    // ---------------- 16-layer column sim (round-8 verified) ----------------
    const int v = bid;

    int s4[4];
    #pragma unroll
    for (int k = 0; k < 4; ++k) s4[k] = SLOT(t + k * 256);
    int sq[4][4];
    #pragma unroll
    for (int pp = 0; pp < 4; ++pp) {
        const int b = 2 * pp;
        const int low = t & ((1 << b) - 1);
        const int i00 = ((t >> b) << (b + 2)) | low;
        sq[pp][0] = SLOT(i00);
        sq[pp][1] = SLOT(i00 | (1 << b));
        sq[pp][2] = SLOT(i00 | (2 << b));
        sq[pp][3] = SLOT(i00 | (3 << b));
    }

    #pragma unroll
    for (int k = 0; k < 4; ++k) {
        int i = t + k * 256;
        st[s4[k]] = make_float2(i == v ? 1.f : 0.f, 0.f);
    }
    __syncthreads();

    for (int l = 0; l < QDEPTH; ++l) {
        const float* gl = gates + l * NW * 8;

        // ---- pass b=8 (wires 0,1) with fused gather of perm l-1 ----
        float2 a00, a01, a10, a11;
        if (l == 0) {
            a00 = st[s4[0]]; a01 = st[s4[1]]; a10 = st[s4[2]]; a11 = st[s4[3]];
        } else {
            const int* ipm = iperm + (l - 1) * DIM;
            int g0 = ipm[t], g1 = ipm[t + 256], g2 = ipm[t + 512], g3 = ipm[t + 768];
            a00 = st[SLOT(g0)]; a01 = st[SLOT(g1)];
            a10 = st[SLOT(g2)]; a11 = st[SLOT(g3)];
        }
        gate2(gl + 0, a00, a10);   // wire 0 (bit 9)
        gate2(gl + 0, a01, a11);
        gate2(gl + 8, a00, a01);   // wire 1 (bit 8)
        gate2(gl + 8, a10, a11);
        if (l) __syncthreads();    // drain gathers before canonical writes
        st[s4[0]] = a00; st[s4[1]] = a01; st[s4[2]] = a10; st[s4[3]] = a11;
        __syncthreads();

        // ---- passes b = 6,4,2,0: thread-exclusive quads ----
        #pragma unroll
        for (int pp = 3; pp >= 0; --pp) {
            const int b = 2 * pp;
            const float* gh = gl + (8 - b) * 8;   // gate on bit b+1 (wire 8-b)
            const float* gm = gl + (9 - b) * 8;   // gate on bit b   (wire 9-b)
            float2 c00 = st[sq[pp][0]], c01 = st[sq[pp][1]];
            float2 c10 = st[sq[pp][2]], c11 = st[sq[pp][3]];
            gate2(gh, c00, c10);
            gate2(gh, c01, c11);
            gate2(gm, c00, c01);
            gate2(gm, c10, c11);
            st[sq[pp][0]] = c00; st[sq[pp][1]] = c01;
            st[sq[pp][2]] = c10; st[sq[pp][3]] = c11;
            __syncthreads();
        }
    }

    // ---- output with fused final perm: Ucol[v][2i]=Re U[i,v], [2i+1]=Im ----
    const int* ipl = iperm + (QDEPTH - 1) * DIM;
    _Float16* col = Ucol + (size_t)v * 2048;
    #pragma unroll
    for (int k = 0; k < 4; ++k) {
        int i = t + k * 256;
        float2 a = st[SLOT(ipl[i])];
        f16x2 p;
        p[0] = (_Float16)a.x;
        p[1] = (_Float16)a.y;
        *(f16x2*)(col + 2 * i) = p;
    }
}

// Split-layout transpose: Bil[j][k] = Ucol[k][2j] (Re), Bil[1024+j][k] = Ucol[k][2j+1].
__global__ __launch_bounds__(256)
void transpose_kernel(const _Float16* __restrict__ Ucol, _Float16* __restrict__ Bil) {
    __shared__ _Float16 tile[64][72];
    const int bx = blockIdx.x;          // c-tile: 64 cols of Ucol = 32 j x {Re,Im}
    const int by = blockIdx.y;          // k-tile: 64 rows of Ucol
    const int t  = threadIdx.x;
    const int r  = t >> 3;              // 0..31
    const int c8 = (t & 7) * 8;         // 0..56

    #pragma unroll
    for (int kk = 0; kk < 64; kk += 32) {
        *(f16x8*)&tile[kk + r][c8] =
            *(const f16x8*)(Ucol + (size_t)(by * 64 + kk + r) * 2048 + bx * 64 + c8);
    }
    __syncthreads();
    // thread -> j-row jj = r (0..31), k-chunk c8; write Re and Im rows
    {
        f16x8 ore, oim;
        #pragma unroll
        for (int u = 0; u < 8; ++u) {
            ore[u] = tile[c8 + u][2 * r];
            oim[u] = tile[c8 + u][2 * r + 1];
        }
        const int j = bx * 32 + r;
        *(f16x8*)(Bil + (size_t)j * 1024 + by * 64 + c8) = ore;
        *(f16x8*)(Bil + (size_t)(1024 + j) * 1024 + by * 64 + c8) = oim;
    }
}

// f16x8 frag read from a [rows][64] half-slot with chunk-XOR swizzle
__device__ __forceinline__ f16x8 ldsfrag(const _Float16* base, int hrow, int c) {
    return *(const f16x8*)(base + hrow * 64 + ((c ^ (hrow & 7)) << 3));
}

// ---------------- Main GEMM: 256-row x 128-j tile, BK=64, 8-phase ----------
// A = Xh (8192x1024). B = Bil split layout: Re rows [j0,j0+128),
// Im rows [1024+j0, 1024+j0+128). Each wave: 128 A-rows x 32 j, holding
// matched Re/Im accumulator pairs -> shfl-free coalesced epilogue.
#define NKT 16     // 1024 / 64

__global__ __launch_bounds__(512, 2)
void gemm_kernel(const _Float16* __restrict__ A, const _Float16* __restrict__ B,
                 const float* __restrict__ invs, float* __restrict__ out) {
    __shared__ _Float16 As[2][2][8192];   // [buf][M-half][128 rows x 64 k], 64 KB
    __shared__ _Float16 Bs[2][2][8192];   // [buf][Re/Im][128 rows x 64 k], 64 KB
    const int t    = threadIdx.x;
    const int lane = t & 63;
    const int wid  = t >> 6;      // 0..7
    const int wm   = wid >> 2;    // 0..1 : M-half (128 rows)
    const int wn   = wid & 3;     // 0..3 : j-slice (32 j)

    // T1: XCD x gets m-panels 4x..4x+3, all 8 j-panels
    const int bid   = blockIdx.x;          // 256 blocks
    const int local = bid >> 3;            // 0..31
    const int m0 = ((bid & 7) * 4 + (local & 3)) * 256;
    const int j0 = (local >> 2) * 128;     // 8 j-panels of 128

    const _Float16* Ag0 = A + (size_t)m0 * 1024;            // A rows m0..+127
    const _Float16* Ag1 = A + (size_t)(m0 + 128) * 1024;    // A rows +128..+255
    const _Float16* Bg0 = B + (size_t)j0 * 1024;            // Re rows j0..+127
    const _Float16* Bg1 = B + (size_t)(1024 + j0) * 1024;   // Im rows

    const int srow = t >> 3;                       // 0..63 (and +64)
    const int sgc  = ((t & 7) ^ (srow & 7)) * 8;   // swizzled source chunk, elems
    #define STAGE_HALF(dst, gbase, kt)                                              \
        do {                                                                        \
            __builtin_amdgcn_global_load_lds(                                       \
                (const __attribute__((address_space(1))) void*)                     \
                    ((gbase) + (size_t)srow * 1024 + (kt) * 64 + sgc),              \
                (__attribute__((address_space(3))) void*)((dst) + t * 8), 16, 0, 0);\
            __builtin_amdgcn_global_load_lds(                                       \
                (const __attribute__((address_space(1))) void*)                     \
                    ((gbase) + (size_t)(64 + srow) * 1024 + (kt) * 64 + sgc),       \
                (__attribute__((address_space(3))) void*)((dst) + 4096 + t * 8),    \
                16, 0, 0);                                                          \
        } while (0)

    // acc[mf][0..1] = Re j-tiles, acc[mf][2..3] = Im j-tiles (same j-slice)
    f32x4 acc[8][4];
    const f32x4 zero = {0.f, 0.f, 0.f, 0.f};
    #pragma unroll
    for (int i = 0; i < 8; ++i)
        #pragma unroll
        for (int j = 0; j < 4; ++j) acc[i][j] = zero;

    const int fr = lane & 15;       // frag row within 16
    const int ch = lane >> 4;       // 16B chunk within 32-k sub-tile
    const int brow = wn * 32;       // wave's B-row base (within each half)

    // ---- prologue: tile 0 fully + A-half0 of tile 1; wait tile 0 only ----
    STAGE_HALF(&As[0][0][0], Ag0, 0);
    STAGE_HALF(&As[0][1][0], Ag1, 0);
    STAGE_HALF(&Bs[0][0][0], Bg0, 0);
    STAGE_HALF(&Bs[0][1][0], Bg1, 0);
    STAGE_HALF(&As[1][0][0], Ag0, 1);
    asm volatile("s_waitcnt vmcnt(2)" ::: "memory");
    __builtin_amdgcn_s_barrier();
    __builtin_amdgcn_sched_barrier(0);

    for (int tk = 0; tk < NKT; ++tk) {
        const int buf = tk & 1, nbuf = buf ^ 1;
        const _Float16* Ab   = &As[buf][wm][0];
        const _Float16* BbRe = &Bs[buf][0][0];
        const _Float16* BbIm = &Bs[buf][1][0];

        f16x8 afl[4][2], afh[4][2], bfa[2][2], bfb[2][2];

        // ---- phase 0: read afl + bfa(Re); stage A-half1(t+1) ----
        #pragma unroll
        for (int m = 0; m < 4; ++m)
            #pragma unroll
            for (int ks = 0; ks < 2; ++ks)
                afl[m][ks] = ldsfrag(Ab, m * 16 + fr, ks * 4 + ch);
        #pragma unroll
        for (int n = 0; n < 2; ++n)
            #pragma unroll
            for (int ks = 0; ks < 2; ++ks)
                bfa[n][ks] = ldsfrag(BbRe, brow + n * 16 + fr, ks * 4 + ch);
        if (tk + 1 < NKT) STAGE_HALF(&As[nbuf][1][0], Ag1, tk + 1);
        __builtin_amdgcn_s_barrier();
        asm volatile("s_waitcnt lgkmcnt(0)" ::: "memory");
        __builtin_amdgcn_sched_barrier(0);
        __builtin_amdgcn_s_setprio(1);
        #pragma unroll
        for (int m = 0; m < 4; ++m)
            #pragma unroll
            for (int n = 0; n < 2; ++n)
                #pragma unroll
                for (int ks = 0; ks < 2; ++ks)
                    acc[m][n] = __builtin_amdgcn_mfma_f32_16x16x32_f16(
                        afl[m][ks], bfa[n][ks], acc[m][n], 0, 0, 0);
        __builtin_amdgcn_s_setprio(0);
        __builtin_amdgcn_s_barrier();
        __builtin_amdgcn_sched_barrier(0);

        // ---- phase 1: read bfb(Im); stage B-Re(t+1) ----
        #pragma unroll
        for (int n = 0; n < 2; ++n)
            #pragma unroll
            for (int ks = 0; ks < 2; ++ks)
                bfb[n][ks] = ldsfrag(BbIm, brow + n * 16 + fr, ks * 4 + ch);
        if (tk + 1 < NKT) STAGE_HALF(&Bs[nbuf][0][0], Bg0, tk + 1);
        __builtin_amdgcn_s_barrier();
        asm volatile("s_waitcnt lgkmcnt(0)" ::: "memory");
        __builtin_amdgcn_sched_barrier(0);
        __builtin_amdgcn_s_setprio(1);
        #pragma unroll
        for (int m = 0; m < 4; ++m)
            #pragma unroll
            for (int n = 0; n < 2; ++n)
                #pragma unroll
                for (int ks = 0; ks < 2; ++ks)
                    acc[m][2 + n] = __builtin_amdgcn_mfma_f32_16x16x32_f16(
                        afl[m][ks], bfb[n][ks], acc[m][2 + n], 0, 0, 0);
        __builtin_amdgcn_s_setprio(0);
        __builtin_amdgcn_s_barrier();
        __builtin_amdgcn_sched_barrier(0);

        // ---- phase 2: read afh; stage B-Im(t+1) ----
        #pragma unroll
        for (int m = 0; m < 4; ++m)
            #pragma unroll
            for (int ks = 0; ks < 2; ++ks)
                afh[m][ks] = ldsfrag(Ab, 64 + m * 16 + fr, ks * 4 + ch);
        if (tk + 1 < NKT) STAGE_HALF(&Bs[nbuf][1][0], Bg1, tk + 1);
        __builtin_amdgcn_s_barrier();
        asm volatile("s_waitcnt lgkmcnt(0)" ::: "memory");
        __builtin_amdgcn_sched_barrier(0);
        __builtin_amdgcn_s_setprio(1);
        #pragma unroll
        for (int m = 0; m < 4; ++m)
            #pragma unroll
            for (int n = 0; n < 2; ++n)
                #pragma unroll
                for (int ks = 0; ks < 2; ++ks)
                    acc[4 + m][n] = __builtin_amdgcn_mfma_f32_16x16x32_f16(
                        afh[m][ks], bfa[n][ks], acc[4 + m][n], 0, 0, 0);
        __builtin_amdgcn_s_setprio(0);
        __builtin_amdgcn_s_barrier();
        __builtin_amdgcn_sched_barrier(0);

        // ---- phase 3: stage A-half0(t+2) into As[buf][0] (dead since p2) ----
        if (tk + 2 < NKT) STAGE_HALF(&As[buf][0][0], Ag0, tk + 2);
        __builtin_amdgcn_s_barrier();
        asm volatile("s_waitcnt lgkmcnt(0)" ::: "memory");
        __builtin_amdgcn_sched_barrier(0);
        __builtin_amdgcn_s_setprio(1);
        #pragma unroll
        for (int m = 0; m < 4; ++m)
            #pragma unroll
            for (int n = 0; n < 2; ++n)
                #pragma unroll
                for (int ks = 0; ks < 2; ++ks)
                    acc[4 + m][2 + n] = __builtin_amdgcn_mfma_f32_16x16x32_f16(
                        afh[m][ks], bfb[n][ks], acc[4 + m][2 + n], 0, 0, 0);
        __builtin_amdgcn_s_setprio(0);
        // boundary: tile t+1 ready when only A0(t+2)'s 2 loads remain in flight
        if (tk + 1 < NKT) {
            if (tk + 2 < NKT) asm volatile("s_waitcnt vmcnt(2)" ::: "memory");
            else              asm volatile("s_waitcnt vmcnt(0)" ::: "memory");
            __builtin_amdgcn_s_barrier();
            __builtin_amdgcn_sched_barrier(0);
        }
    }
    #undef STAGE_HALF

    // ---- epilogue: shfl-free. row = m0+wm*128+mf*16+(lane>>4)*4+r ;
    //      j = j0 + wn*32 + nf*16 + (lane&15). All 64 lanes store. ----
    const int colf = lane & 15;
    const int rowf = (lane >> 4) * 4;
    #pragma unroll
    for (int mf = 0; mf < 8; ++mf) {
        #pragma unroll
        for (int nf = 0; nf < 2; ++nf) {
            const int j = j0 + wn * 32 + nf * 16 + colf;
            #pragma unroll
            for (int r = 0; r < 4; ++r) {
                const int row = m0 + wm * 128 + mf * 16 + rowf + r;
                float re = acc[mf][nf][r];
                float im = acc[mf][2 + nf][r];
                float p = fminf((re * re + im * im) * invs[row], 1.0f);
                out[(size_t)row * DIM + j] = p;
            }
        }
    }
}

extern "C" void kernel_launch(void* const* d_in, const int* in_sizes, int n_in,
                              void* d_out, int out_size, void* d_ws, size_t ws_size,
                              hipStream_t stream) {
    const float* x = (const float*)d_in[0];     // (8192,1,32,32) fp32
    const float* w = (const float*)d_in[1];     // (16,10,3) fp32
    float* out = (float*)d_out;                 // (8192,1,32,32) fp32

    char* ws = (char*)d_ws;
    float*     gates = (float*)(ws + WS_GATES);
    int*       iperm = (int*)(ws + WS_IPERM);
    float*     invs  = (float*)(ws + WS_INVS);
    _Float16*  Xh    = (_Float16*)(ws + WS_XH);
    _Float16*  Bil   = (_Float16*)(ws + WS_BIL);
    // Ucol scratch lives in d_out (4 MB of its 32 MB); consumed by transpose
    // before gemm overwrites every element of d_out.
    _Float16*  Ucol  = (_Float16*)d_out;

    prep_kernel<<<1, 1024, 0, stream>>>(w, gates, iperm);
    fused_sim_kernel<<<3072, 256, 0, stream>>>(gates, iperm, Ucol, x, Xh, invs);
    transpose_kernel<<<dim3(32, 16), 256, 0, stream>>>(Ucol, Bil);
    gemm_kernel<<<256, 512, 0, stream>>>(Xh, Bil, invs, out);
}

// Round 14
// 112.247 us; speedup vs baseline: 1.3690x; 1.0137x over previous
//
#include <hip/hip_runtime.h>
#include <math.h>

#define NW     10
#define DIM    1024
#define QDEPTH 16

typedef __attribute__((ext_vector_type(8))) _Float16 f16x8;
typedef __attribute__((ext_vector_type(4))) _Float16 f16x4;
typedef __attribute__((ext_vector_type(2))) _Float16 f16x2;
typedef __attribute__((ext_vector_type(4))) float    f32x4;

// ---------------- ws layout ----------------
#define WS_GATES 0
#define WS_IPERM 8192
#define WS_INVS  81920
#define WS_XH    (1u << 20)     // 16 MB
#define WS_BIL   (17u << 20)    // 4 MB  (rows 0..1023 = Re U, 1024..2047 = Im U)
// d_out scratch: Ucol @0 (4 MB), consumed by transpose before gemm overwrites.

// padded LDS slot: breaks power-of-2 stride bank conflicts
#define SLOT(i) ((i) + ((i) >> 4))

__device__ inline void gate2(const float* __restrict__ g, float2& p0, float2& p1) {
    float m00r = g[0], m00i = g[1], m01r = g[2], m01i = g[3];
    float m10r = g[4], m10i = g[5], m11r = g[6], m11i = g[7];
    float n0x = m00r*p0.x - m00i*p0.y + m01r*p1.x - m01i*p1.y;
    float n0y = m00r*p0.y + m00i*p0.x + m01r*p1.y + m01i*p1.x;
    float n1x = m10r*p0.x - m10i*p0.y + m11r*p1.x - m11i*p1.y;
    float n1y = m10r*p0.y + m10i*p0.x + m11r*p1.y + m11i*p1.x;
    p0 = make_float2(n0x, n0y);
    p1 = make_float2(n1x, n1y);
}

__global__ __launch_bounds__(1024)
void prep_kernel(const float* __restrict__ w, float* __restrict__ gates,
                 int* __restrict__ iperm) {
    int t = threadIdx.x;
    const float PI = 3.14159265358979323846f;
    if (t < QDEPTH * NW) {
        // Rot(phi,theta,omega) = RZ(omega) RY(theta) RZ(phi); angles = tanh(w)*pi
        float phi   = tanhf(w[t*3 + 0]) * PI;
        float theta = tanhf(w[t*3 + 1]) * PI;
        float omega = tanhf(w[t*3 + 2]) * PI;
        float ch = cosf(theta * 0.5f), sh = sinf(theta * 0.5f);
        float ap = (phi + omega) * 0.5f;
        float am = (phi - omega) * 0.5f;
        float* g = gates + t * 8;
        g[0] =  cosf(ap) * ch;  g[1] = -sinf(ap) * ch;   // m00
        g[2] = -cosf(am) * sh;  g[3] = -sinf(am) * sh;   // m01
        g[4] =  cosf(am) * sh;  g[5] = -sinf(am) * sh;   // m10
        g[6] =  cosf(ap) * ch;  g[7] =  sinf(ap) * ch;   // m11
    }
    // Forward CNOT-block gather (round-1 verified): state'[v] = state[G_l(v)]
    int v = t;
    for (int l = 0; l < QDEPTH; ++l) {
        int r = (l % (NW - 1)) + 1;
        int u = v;
        for (int wq = NW - 1; wq >= 0; --wq) {
            int bc = 9 - wq;
            int bt = 9 - ((wq + r) % NW);
            u ^= ((u >> bc) & 1) << bt;
        }
        iperm[l * DIM + v] = u;
    }
}

// Fused: 3072 blocks.
//   bid < 1024        : 16-layer column sim -> Ucol row bid
//   bid in [1024,3072): normcast for batch rows 4*(bid-1024)..+3
// Barrier structure (NEW): quad passes (b=6,4,2,0) are provably wave-local —
// reader t at pass b touches only i[9:8]=t[7:6], and the prior quad pass's
// writer of any such i is in the same wave. So quad passes use wave-sync
// lgkmcnt(0) only; s_barrier remains solely around the cross-wave b=8 session
// (perm gather + canonical scatter): 3 barriers/layer instead of 6.
__global__ __launch_bounds__(256)
void fused_sim_kernel(const float* __restrict__ gates, const int* __restrict__ iperm,
                      _Float16* __restrict__ Ucol,
                      const float* __restrict__ x, _Float16* __restrict__ Xh,
                      float* __restrict__ invs) {
    __shared__ float2 st[DIM + 64];
    const int bid = blockIdx.x;
    const int t   = threadIdx.x;

    if (bid >= 1024) {
        // ---------------- normcast: 4 rows per block, 1 wave per row --------
        const int b = (bid - 1024) * 4 + (t >> 6);
        const int l = t & 63;
        const float4* xr = (const float4*)(x + (size_t)b * DIM);
        float4 v[4];
        float ss = 0.f;
        #pragma unroll
        for (int c = 0; c < 4; ++c) {
            v[c] = xr[l + c * 64];
            ss += v[c].x*v[c].x + v[c].y*v[c].y + v[c].z*v[c].z + v[c].w*v[c].w;
        }
        #pragma unroll
        for (int o = 32; o >= 1; o >>= 1) ss += __shfl_down(ss, o, 64);
        ss = __shfl(ss, 0, 64);
        if (l == 0) invs[b] = 1024.0f / ss;
        f16x4* xo = (f16x4*)(Xh + (size_t)b * DIM);
        #pragma unroll
        for (int c = 0; c < 4; ++c) {
            f16x4 h;
            h[0] = (_Float16)v[c].x; h[1] = (_Float16)v[c].y;
            h[2] = (_Float16)v[c].z; h[3] = (_Float16)v[c].w;
            xo[l + c * 64] = h;
        }
        return;
    }

    // ---------------- 16-layer column sim ----------------
    const int v = bid;

    int s4[4];
    #pragma unroll
    for (int k = 0; k < 4; ++k) s4[k] = SLOT(t + k * 256);
    int sq[4][4];
    #pragma unroll
    for (int pp = 0; pp < 4; ++pp) {
        const int b = 2 * pp;
        const int low = t & ((1 << b) - 1);
        const int i00 = ((t >> b) << (b + 2)) | low;
        sq[pp][0] = SLOT(i00);
        sq[pp][1] = SLOT(i00 | (1 << b));
        sq[pp][2] = SLOT(i00 | (2 << b));
        sq[pp][3] = SLOT(i00 | (3 << b));
    }

    #pragma unroll
    for (int k = 0; k < 4; ++k) {
        int i = t + k * 256;
        st[s4[k]] = make_float2(i == v ? 1.f : 0.f, 0.f);
    }
    __syncthreads();

    // perm indices for the NEXT layer's gather, prefetched one layer ahead
    int pg0 = 0, pg1 = 0, pg2 = 0, pg3 = 0;

    for (int l = 0; l < QDEPTH; ++l) {
        const float* gl = gates + l * NW * 8;

        // ---- barrier: all waves' quad-pass writes visible before cross-wave
        //      gather (l>0). l==0 reads are thread-local (own init writes).
        if (l) __syncthreads();

        // ---- b=8 session (wires 0,1) with fused gather of perm l-1 ----
        float2 a00, a01, a10, a11;
        if (l == 0) {
            a00 = st[s4[0]]; a01 = st[s4[1]]; a10 = st[s4[2]]; a11 = st[s4[3]];
        } else {
            a00 = st[SLOT(pg0)]; a01 = st[SLOT(pg1)];
            a10 = st[SLOT(pg2)]; a11 = st[SLOT(pg3)];
        }
        // prefetch perm row l (used at layer l+1, or by the output for l=15)
        {
            const int* ipn = iperm + l * DIM;
            pg0 = ipn[t]; pg1 = ipn[t + 256]; pg2 = ipn[t + 512]; pg3 = ipn[t + 768];
        }
        gate2(gl + 0, a00, a10);   // wire 0 (bit 9)
        gate2(gl + 0, a01, a11);
        gate2(gl + 8, a00, a01);   // wire 1 (bit 8)
        gate2(gl + 8, a10, a11);
        if (l) __syncthreads();    // drain all gather reads before overwrite
        st[s4[0]] = a00; st[s4[1]] = a01; st[s4[2]] = a10; st[s4[3]] = a11;
        __syncthreads();           // cross-wave scatter visible to all waves

        // ---- quad passes b = 6,4,2,0: wave-local exchange, no s_barrier ----
        #pragma unroll
        for (int pp = 3; pp >= 0; --pp) {
            const int b = 2 * pp;
            const float* gh = gl + (8 - b) * 8;   // gate on bit b+1 (wire 8-b)
            const float* gm = gl + (9 - b) * 8;   // gate on bit b   (wire 9-b)
            float2 c00 = st[sq[pp][0]], c01 = st[sq[pp][1]];
            float2 c10 = st[sq[pp][2]], c11 = st[sq[pp][3]];
            gate2(gh, c00, c10);
            gate2(gh, c01, c11);
            gate2(gm, c00, c01);
            gate2(gm, c10, c11);
            st[sq[pp][0]] = c00; st[sq[pp][1]] = c01;
            st[sq[pp][2]] = c10; st[sq[pp][3]] = c11;
            // wave-synchronous: next pass reads only slots written by this
            // wave (i[9:8]=wave id). Ensure writes complete; pin ordering.
            asm volatile("s_waitcnt lgkmcnt(0)" ::: "memory");
            __builtin_amdgcn_sched_barrier(0);
        }
    }

    // ---- output with fused final perm (row 15, already in pg*) ----
    __syncthreads();   // all waves' last quad-pass writes visible (cross-wave gather)
    _Float16* col = Ucol + (size_t)v * 2048;
    {
        float2 a0 = st[SLOT(pg0)], a1 = st[SLOT(pg1)];
        float2 a2 = st[SLOT(pg2)], a3 = st[SLOT(pg3)];
        f16x2 p0, p1, p2, p3;
        p0[0] = (_Float16)a0.x; p0[1] = (_Float16)a0.y;
        p1[0] = (_Float16)a1.x; p1[1] = (_Float16)a1.y;
        p2[0] = (_Float16)a2.x; p2[1] = (_Float16)a2.y;
        p3[0] = (_Float16)a3.x; p3[1] = (_Float16)a3.y;
        *(f16x2*)(col + 2 * t)         = p0;
        *(f16x2*)(col + 2 * (t + 256)) = p1;
        *(f16x2*)(col + 2 * (t + 512)) = p2;
        *(f16x2*)(col + 2 * (t + 768)) = p3;
    }
}

// Split-layout transpose: Bil[j][k] = Ucol[k][2j] (Re), Bil[1024+j][k] = Ucol[k][2j+1].
__global__ __launch_bounds__(256)
void transpose_kernel(const _Float16* __restrict__ Ucol, _Float16* __restrict__ Bil) {
    __shared__ _Float16 tile[64][72];
    const int bx = blockIdx.x;          // c-tile: 64 cols of Ucol = 32 j x {Re,Im}
    const int by = blockIdx.y;          // k-tile: 64 rows of Ucol
    const int t  = threadIdx.x;
    const int r  = t >> 3;              // 0..31
    const int c8 = (t & 7) * 8;         // 0..56

    #pragma unroll
    for (int kk = 0; kk < 64; kk += 32) {
        *(f16x8*)&tile[kk + r][c8] =
            *(const f16x8*)(Ucol + (size_t)(by * 64 + kk + r) * 2048 + bx * 64 + c8);
    }
    __syncthreads();
    {
        f16x8 ore, oim;
        #pragma unroll
        for (int u = 0; u < 8; ++u) {
            ore[u] = tile[c8 + u][2 * r];
            oim[u] = tile[c8 + u][2 * r + 1];
        }
        const int j = bx * 32 + r;
        *(f16x8*)(Bil + (size_t)j * 1024 + by * 64 + c8) = ore;
        *(f16x8*)(Bil + (size_t)(1024 + j) * 1024 + by * 64 + c8) = oim;
    }
}

// f16x8 frag read from a [rows][64] half-slot with chunk-XOR swizzle
__device__ __forceinline__ f16x8 ldsfrag(const _Float16* base, int hrow, int c) {
    return *(const f16x8*)(base + hrow * 64 + ((c ^ (hrow & 7)) << 3));
}

// ---------------- Main GEMM: 256-row x 128-j tile, BK=64, 8-phase ----------
// A = Xh (8192x1024). B = Bil split layout: Re rows [j0,j0+128),
// Im rows [1024+j0, 1024+j0+128). Each wave: 128 A-rows x 32 j, holding
// matched Re/Im accumulator pairs -> shfl-free coalesced epilogue.
#define NKT 16     // 1024 / 64

__global__ __launch_bounds__(512, 2)
void gemm_kernel(const _Float16* __restrict__ A, const _Float16* __restrict__ B,
                 const float* __restrict__ invs, float* __restrict__ out) {
    __shared__ _Float16 As[2][2][8192];   // [buf][M-half][128 rows x 64 k], 64 KB
    __shared__ _Float16 Bs[2][2][8192];   // [buf][Re/Im][128 rows x 64 k], 64 KB
    const int t    = threadIdx.x;
    const int lane = t & 63;
    const int wid  = t >> 6;      // 0..7
    const int wm   = wid >> 2;    // 0..1 : M-half (128 rows)
    const int wn   = wid & 3;     // 0..3 : j-slice (32 j)

    // T1: XCD x gets m-panels 4x..4x+3, all 8 j-panels
    const int bid   = blockIdx.x;          // 256 blocks
    const int local = bid >> 3;            // 0..31
    const int m0 = ((bid & 7) * 4 + (local & 3)) * 256;
    const int j0 = (local >> 2) * 128;     // 8 j-panels of 128

    const _Float16* Ag0 = A + (size_t)m0 * 1024;            // A rows m0..+127
    const _Float16* Ag1 = A + (size_t)(m0 + 128) * 1024;    // A rows +128..+255
    const _Float16* Bg0 = B + (size_t)j0 * 1024;            // Re rows j0..+127
    const _Float16* Bg1 = B + (size_t)(1024 + j0) * 1024;   // Im rows

    const int srow = t >> 3;                       // 0..63 (and +64)
    const int sgc  = ((t & 7) ^ (srow & 7)) * 8;   // swizzled source chunk, elems
    #define STAGE_HALF(dst, gbase, kt)                                              \
        do {                                                                        \
            __builtin_amdgcn_global_load_lds(                                       \
                (const __attribute__((address_space(1))) void*)                     \
                    ((gbase) + (size_t)srow * 1024 + (kt) * 64 + sgc),              \
                (__attribute__((address_space(3))) void*)((dst) + t * 8), 16, 0, 0);\
            __builtin_amdgcn_global_load_lds(                                       \
                (const __attribute__((address_space(1))) void*)                     \
                    ((gbase) + (size_t)(64 + srow) * 1024 + (kt) * 64 + sgc),       \
                (__attribute__((address_space(3))) void*)((dst) + 4096 + t * 8),    \
                16, 0, 0);                                                          \
        } while (0)

    // acc[mf][0..1] = Re j-tiles, acc[mf][2..3] = Im j-tiles (same j-slice)
    f32x4 acc[8][4];
    const f32x4 zero = {0.f, 0.f, 0.f, 0.f};
    #pragma unroll
    for (int i = 0; i < 8; ++i)
        #pragma unroll
        for (int j = 0; j < 4; ++j) acc[i][j] = zero;

    const int fr = lane & 15;       // frag row within 16
    const int ch = lane >> 4;       // 16B chunk within 32-k sub-tile
    const int brow = wn * 32;       // wave's B-row base (within each half)

    // ---- prologue: tile 0 fully + A-half0 of tile 1; wait tile 0 only ----
    STAGE_HALF(&As[0][0][0], Ag0, 0);
    STAGE_HALF(&As[0][1][0], Ag1, 0);
    STAGE_HALF(&Bs[0][0][0], Bg0, 0);
    STAGE_HALF(&Bs[0][1][0], Bg1, 0);
    STAGE_HALF(&As[1][0][0], Ag0, 1);
    asm volatile("s_waitcnt vmcnt(2)" ::: "memory");
    __builtin_amdgcn_s_barrier();
    __builtin_amdgcn_sched_barrier(0);

    for (int tk = 0; tk < NKT; ++tk) {
        const int buf = tk & 1, nbuf = buf ^ 1;
        const _Float16* Ab   = &As[buf][wm][0];
        const _Float16* BbRe = &Bs[buf][0][0];
        const _Float16* BbIm = &Bs[buf][1][0];

        f16x8 afl[4][2], afh[4][2], bfa[2][2], bfb[2][2];

        // ---- phase 0: read afl + bfa(Re); stage A-half1(t+1) ----
        #pragma unroll
        for (int m = 0; m < 4; ++m)
            #pragma unroll
            for (int ks = 0; ks < 2; ++ks)
                afl[m][ks] = ldsfrag(Ab, m * 16 + fr, ks * 4 + ch);
        #pragma unroll
        for (int n = 0; n < 2; ++n)
            #pragma unroll
            for (int ks = 0; ks < 2; ++ks)
                bfa[n][ks] = ldsfrag(BbRe, brow + n * 16 + fr, ks * 4 + ch);
        if (tk + 1 < NKT) STAGE_HALF(&As[nbuf][1][0], Ag1, tk + 1);
        __builtin_amdgcn_s_barrier();
        asm volatile("s_waitcnt lgkmcnt(0)" ::: "memory");
        __builtin_amdgcn_sched_barrier(0);
        __builtin_amdgcn_s_setprio(1);
        #pragma unroll
        for (int m = 0; m < 4; ++m)
            #pragma unroll
            for (int n = 0; n < 2; ++n)
                #pragma unroll
                for (int ks = 0; ks < 2; ++ks)
                    acc[m][n] = __builtin_amdgcn_mfma_f32_16x16x32_f16(
                        afl[m][ks], bfa[n][ks], acc[m][n], 0, 0, 0);
        __builtin_amdgcn_s_setprio(0);
        __builtin_amdgcn_s_barrier();
        __builtin_amdgcn_sched_barrier(0);

        // ---- phase 1: read bfb(Im); stage B-Re(t+1) ----
        #pragma unroll
        for (int n = 0; n < 2; ++n)
            #pragma unroll
            for (int ks = 0; ks < 2; ++ks)
                bfb[n][ks] = ldsfrag(BbIm, brow + n * 16 + fr, ks * 4 + ch);
        if (tk + 1 < NKT) STAGE_HALF(&Bs[nbuf][0][0], Bg0, tk + 1);
        __builtin_amdgcn_s_barrier();
        asm volatile("s_waitcnt lgkmcnt(0)" ::: "memory");
        __builtin_amdgcn_sched_barrier(0);
        __builtin_amdgcn_s_setprio(1);
        #pragma unroll
        for (int m = 0; m < 4; ++m)
            #pragma unroll
            for (int n = 0; n < 2; ++n)
                #pragma unroll
                for (int ks = 0; ks < 2; ++ks)
                    acc[m][2 + n] = __builtin_amdgcn_mfma_f32_16x16x32_f16(
                        afl[m][ks], bfb[n][ks], acc[m][2 + n], 0, 0, 0);
        __builtin_amdgcn_s_setprio(0);
        __builtin_amdgcn_s_barrier();
        __builtin_amdgcn_sched_barrier(0);

        // ---- phase 2: read afh; stage B-Im(t+1) ----
        #pragma unroll
        for (int m = 0; m < 4; ++m)
            #pragma unroll
            for (int ks = 0; ks < 2; ++ks)
                afh[m][ks] = ldsfrag(Ab, 64 + m * 16 + fr, ks * 4 + ch);
        if (tk + 1 < NKT) STAGE_HALF(&Bs[nbuf][1][0], Bg1, tk + 1);
        __builtin_amdgcn_s_barrier();
        asm volatile("s_waitcnt lgkmcnt(0)" ::: "memory");
        __builtin_amdgcn_sched_barrier(0);
        __builtin_amdgcn_s_setprio(1);
        #pragma unroll
        for (int m = 0; m < 4; ++m)
            #pragma unroll
            for (int n = 0; n < 2; ++n)
                #pragma unroll
                for (int ks = 0; ks < 2; ++ks)
                    acc[4 + m][n] = __builtin_amdgcn_mfma_f32_16x16x32_f16(
                        afh[m][ks], bfa[n][ks], acc[4 + m][n], 0, 0, 0);
        __builtin_amdgcn_s_setprio(0);
        __builtin_amdgcn_s_barrier();
        __builtin_amdgcn_sched_barrier(0);

        // ---- phase 3: stage A-half0(t+2) into As[buf][0] (dead since p2) ----
        if (tk + 2 < NKT) STAGE_HALF(&As[buf][0][0], Ag0, tk + 2);
        __builtin_amdgcn_s_barrier();
        asm volatile("s_waitcnt lgkmcnt(0)" ::: "memory");
        __builtin_amdgcn_sched_barrier(0);
        __builtin_amdgcn_s_setprio(1);
        #pragma unroll
        for (int m = 0; m < 4; ++m)
            #pragma unroll
            for (int n = 0; n < 2; ++n)
                #pragma unroll
                for (int ks = 0; ks < 2; ++ks)
                    acc[4 + m][2 + n] = __builtin_amdgcn_mfma_f32_16x16x32_f16(
                        afh[m][ks], bfb[n][ks], acc[4 + m][2 + n], 0, 0, 0);
        __builtin_amdgcn_s_setprio(0);
        // boundary: tile t+1 ready when only A0(t+2)'s 2 loads remain in flight
        if (tk + 1 < NKT) {
            if (tk + 2 < NKT) asm volatile("s_waitcnt vmcnt(2)" ::: "memory");
            else              asm volatile("s_waitcnt vmcnt(0)" ::: "memory");
            __builtin_amdgcn_s_barrier();
            __builtin_amdgcn_sched_barrier(0);
        }
    }
    #undef STAGE_HALF

    // ---- epilogue: shfl-free. row = m0+wm*128+mf*16+(lane>>4)*4+r ;
    //      j = j0 + wn*32 + nf*16 + (lane&15). All 64 lanes store. ----
    const int colf = lane & 15;
    const int rowf = (lane >> 4) * 4;
    #pragma unroll
    for (int mf = 0; mf < 8; ++mf) {
        #pragma unroll
        for (int nf = 0; nf < 2; ++nf) {
            const int j = j0 + wn * 32 + nf * 16 + colf;
            #pragma unroll
            for (int r = 0; r < 4; ++r) {
                const int row = m0 + wm * 128 + mf * 16 + rowf + r;
                float re = acc[mf][nf][r];
                float im = acc[mf][2 + nf][r];
                float p = fminf((re * re + im * im) * invs[row], 1.0f);
                out[(size_t)row * DIM + j] = p;
            }
        }
    }
}

extern "C" void kernel_launch(void* const* d_in, const int* in_sizes, int n_in,
                              void* d_out, int out_size, void* d_ws, size_t ws_size,
                              hipStream_t stream) {
    const float* x = (const float*)d_in[0];     // (8192,1,32,32) fp32
    const float* w = (const float*)d_in[1];     // (16,10,3) fp32
    float* out = (float*)d_out;                 // (8192,1,32,32) fp32

    char* ws = (char*)d_ws;
    float*     gates = (float*)(ws + WS_GATES);
    int*       iperm = (int*)(ws + WS_IPERM);
    float*     invs  = (float*)(ws + WS_INVS);
    _Float16*  Xh    = (_Float16*)(ws + WS_XH);
    _Float16*  Bil   = (_Float16*)(ws + WS_BIL);
    // Ucol scratch lives in d_out (4 MB of its 32 MB); consumed by transpose
    // before gemm overwrites every element of d_out.
    _Float16*  Ucol  = (_Float16*)d_out;

    prep_kernel<<<1, 1024, 0, stream>>>(w, gates, iperm);
    fused_sim_kernel<<<3072, 256, 0, stream>>>(gates, iperm, Ucol, x, Xh, invs);
    transpose_kernel<<<dim3(32, 16), 256, 0, stream>>>(Ucol, Bil);
    gemm_kernel<<<256, 512, 0, stream>>>(Xh, Bil, invs, out);
}

// Round 15
// 98.789 us; speedup vs baseline: 1.5556x; 1.1362x over previous
//
#include <hip/hip_runtime.h>
#include <math.h>

#define NW     10
#define DIM    1024
#define QDEPTH 16

typedef __attribute__((ext_vector_type(8))) _Float16 f16x8;
typedef __attribute__((ext_vector_type(4))) _Float16 f16x4;
typedef __attribute__((ext_vector_type(2))) _Float16 f16x2;
typedef __attribute__((ext_vector_type(4))) float    f32x4;
typedef __attribute__((ext_vector_type(2))) float    f32x2;

// ---------------- ws layout ----------------
#define WS_GATES 0
#define WS_IPERM 8192
#define WS_INVS  81920
#define WS_XH    (1u << 20)     // 16 MB
#define WS_BIL   (17u << 20)    // 4 MB  (rows 0..1023 = Re U, 1024..2047 = Im U)
// d_out scratch: Ucol @0 (4 MB), consumed by transpose before gemm overwrites.

// padded LDS slot: breaks power-of-2 stride bank conflicts
#define SLOT(i) ((i) + ((i) >> 4))

// Packed complex gate: new0 = m00*p0 + m01*p1, new1 = m10*p0 + m11*p1.
// m*p = mr*(x,y) + mi*(-y,x) -> f32x2 elementwise FMAs lower to v_pk_fma_f32
// (2 f32 FMA/inst); coefficients are wave-uniform scalars (SGPR broadcast).
__device__ __forceinline__ void gate2(const float* __restrict__ g, f32x2& p0, f32x2& p1) {
    f32x2 s0; s0.x = -p0.y; s0.y = p0.x;   // i*p0
    f32x2 s1; s1.x = -p1.y; s1.y = p1.x;   // i*p1
    f32x2 n0 = g[0]*p0 + g[1]*s0 + g[2]*p1 + g[3]*s1;
    f32x2 n1 = g[4]*p0 + g[5]*s0 + g[6]*p1 + g[7]*s1;
    p0 = n0; p1 = n1;
}

__global__ __launch_bounds__(1024)
void prep_kernel(const float* __restrict__ w, float* __restrict__ gates,
                 int* __restrict__ iperm) {
    int t = threadIdx.x;
    const float PI = 3.14159265358979323846f;
    if (t < QDEPTH * NW) {
        // Rot(phi,theta,omega) = RZ(omega) RY(theta) RZ(phi); angles = tanh(w)*pi
        float phi   = tanhf(w[t*3 + 0]) * PI;
        float theta = tanhf(w[t*3 + 1]) * PI;
        float omega = tanhf(w[t*3 + 2]) * PI;
        float ch = cosf(theta * 0.5f), sh = sinf(theta * 0.5f);
        float ap = (phi + omega) * 0.5f;
        float am = (phi - omega) * 0.5f;
        float* g = gates + t * 8;
        g[0] =  cosf(ap) * ch;  g[1] = -sinf(ap) * ch;   // m00
        g[2] = -cosf(am) * sh;  g[3] = -sinf(am) * sh;   // m01
        g[4] =  cosf(am) * sh;  g[5] = -sinf(am) * sh;   // m10
        g[6] =  cosf(ap) * ch;  g[7] =  sinf(ap) * ch;   // m11
    }
    // Forward CNOT-block gather (round-1 verified): state'[v] = state[G_l(v)]
    int v = t;
    for (int l = 0; l < QDEPTH; ++l) {
        int r = (l % (NW - 1)) + 1;
        int u = v;
        for (int wq = NW - 1; wq >= 0; --wq) {
            int bc = 9 - wq;
            int bt = 9 - ((wq + r) % NW);
            u ^= ((u >> bc) & 1) << bt;
        }
        iperm[l * DIM + v] = u;
    }
}

// Fused: 3072 blocks.
//   bid < 1024        : 16-layer column sim -> Ucol row bid
//   bid in [1024,3072): normcast for batch rows 4*(bid-1024)..+3
// Quad passes (b=6,4,2,0) are wave-local (reader t touches only i[9:8]=t[7:6],
// written by the same wave in the prior pass) -> wave-sync lgkmcnt(0) only;
// s_barrier only around the cross-wave b=8 session (perm gather + scatter).
__global__ __launch_bounds__(256)
void fused_sim_kernel(const float* __restrict__ gates, const int* __restrict__ iperm,
                      _Float16* __restrict__ Ucol,
                      const float* __restrict__ x, _Float16* __restrict__ Xh,
                      float* __restrict__ invs) {
    __shared__ f32x2 st[DIM + 64];
    const int bid = blockIdx.x;
    const int t   = threadIdx.x;

    if (bid >= 1024) {
        // ---------------- normcast: 4 rows per block, 1 wave per row --------
        const int b = (bid - 1024) * 4 + (t >> 6);
        const int l = t & 63;
        const float4* xr = (const float4*)(x + (size_t)b * DIM);
        float4 v[4];
        float ss = 0.f;
        #pragma unroll
        for (int c = 0; c < 4; ++c) {
            v[c] = xr[l + c * 64];
            ss += v[c].x*v[c].x + v[c].y*v[c].y + v[c].z*v[c].z + v[c].w*v[c].w;
        }
        #pragma unroll
        for (int o = 32; o >= 1; o >>= 1) ss += __shfl_down(ss, o, 64);
        ss = __shfl(ss, 0, 64);
        if (l == 0) invs[b] = 1024.0f / ss;
        f16x4* xo = (f16x4*)(Xh + (size_t)b * DIM);
        #pragma unroll
        for (int c = 0; c < 4; ++c) {
            f16x4 h;
            h[0] = (_Float16)v[c].x; h[1] = (_Float16)v[c].y;
            h[2] = (_Float16)v[c].z; h[3] = (_Float16)v[c].w;
            xo[l + c * 64] = h;
        }
        return;
    }

    // ---------------- 16-layer column sim ----------------
    const int v = bid;

    int s4[4];
    #pragma unroll
    for (int k = 0; k < 4; ++k) s4[k] = SLOT(t + k * 256);
    int sq[4][4];
    #pragma unroll
    for (int pp = 0; pp < 4; ++pp) {
        const int b = 2 * pp;
        const int low = t & ((1 << b) - 1);
        const int i00 = ((t >> b) << (b + 2)) | low;
        sq[pp][0] = SLOT(i00);
        sq[pp][1] = SLOT(i00 | (1 << b));
        sq[pp][2] = SLOT(i00 | (2 << b));
        sq[pp][3] = SLOT(i00 | (3 << b));
    }

    #pragma unroll
    for (int k = 0; k < 4; ++k) {
        int i = t + k * 256;
        f32x2 e; e.x = (i == v) ? 1.f : 0.f; e.y = 0.f;
        st[s4[k]] = e;
    }
    __syncthreads();

    // perm indices for the NEXT layer's gather, prefetched one layer ahead
    int pg0 = 0, pg1 = 0, pg2 = 0, pg3 = 0;

    for (int l = 0; l < QDEPTH; ++l) {
        const float* gl = gates + l * NW * 8;

        // ---- barrier: all waves' quad-pass writes visible before cross-wave
        //      gather (l>0). l==0 reads are thread-local (own init writes).
        if (l) __syncthreads();

        // ---- b=8 session (wires 0,1) with fused gather of perm l-1 ----
        f32x2 a00, a01, a10, a11;
        if (l == 0) {
            a00 = st[s4[0]]; a01 = st[s4[1]]; a10 = st[s4[2]]; a11 = st[s4[3]];
        } else {
            a00 = st[SLOT(pg0)]; a01 = st[SLOT(pg1)];
            a10 = st[SLOT(pg2)]; a11 = st[SLOT(pg3)];
        }
        // prefetch perm row l (used at layer l+1, or by the output for l=15)
        {
            const int* ipn = iperm + l * DIM;
            pg0 = ipn[t]; pg1 = ipn[t + 256]; pg2 = ipn[t + 512]; pg3 = ipn[t + 768];
        }
        gate2(gl + 0, a00, a10);   // wire 0 (bit 9)
        gate2(gl + 0, a01, a11);
        gate2(gl + 8, a00, a01);   // wire 1 (bit 8)
        gate2(gl + 8, a10, a11);
        if (l) __syncthreads();    // drain all gather reads before overwrite
        st[s4[0]] = a00; st[s4[1]] = a01; st[s4[2]] = a10; st[s4[3]] = a11;
        __syncthreads();           // cross-wave scatter visible to all waves

        // ---- quad passes b = 6,4,2,0: wave-local exchange, no s_barrier ----
        #pragma unroll
        for (int pp = 3; pp >= 0; --pp) {
            const int b = 2 * pp;
            const float* gh = gl + (8 - b) * 8;   // gate on bit b+1 (wire 8-b)
            const float* gm = gl + (9 - b) * 8;   // gate on bit b   (wire 9-b)
            f32x2 c00 = st[sq[pp][0]], c01 = st[sq[pp][1]];
            f32x2 c10 = st[sq[pp][2]], c11 = st[sq[pp][3]];
            gate2(gh, c00, c10);
            gate2(gh, c01, c11);
            gate2(gm, c00, c01);
            gate2(gm, c10, c11);
            st[sq[pp][0]] = c00; st[sq[pp][1]] = c01;
            st[sq[pp][2]] = c10; st[sq[pp][3]] = c11;
            // wave-synchronous: next pass reads only slots written by this
            // wave (i[9:8]=wave id). Ensure writes complete; pin ordering.
            asm volatile("s_waitcnt lgkmcnt(0)" ::: "memory");
            __builtin_amdgcn_sched_barrier(0);
        }
    }

    // ---- output with fused final perm (row 15, already in pg*) ----
    __syncthreads();   // all waves' last quad-pass writes visible (cross-wave gather)
    _Float16* col = Ucol + (size_t)v * 2048;
    {
        f32x2 a0 = st[SLOT(pg0)], a1 = st[SLOT(pg1)];
        f32x2 a2 = st[SLOT(pg2)], a3 = st[SLOT(pg3)];
        f16x2 p0, p1, p2, p3;
        p0[0] = (_Float16)a0.x; p0[1] = (_Float16)a0.y;
        p1[0] = (_Float16)a1.x; p1[1] = (_Float16)a1.y;
        p2[0] = (_Float16)a2.x; p2[1] = (_Float16)a2.y;
        p3[0] = (_Float16)a3.x; p3[1] = (_Float16)a3.y;
        *(f16x2*)(col + 2 * t)         = p0;
        *(f16x2*)(col + 2 * (t + 256)) = p1;
        *(f16x2*)(col + 2 * (t + 512)) = p2;
        *(f16x2*)(col + 2 * (t + 768)) = p3;
    }
}

// Split-layout transpose: Bil[j][k] = Ucol[k][2j] (Re), Bil[1024+j][k] = Ucol[k][2j+1].
__global__ __launch_bounds__(256)
void transpose_kernel(const _Float16* __restrict__ Ucol, _Float16* __restrict__ Bil) {
    __shared__ _Float16 tile[64][72];
    const int bx = blockIdx.x;          // c-tile: 64 cols of Ucol = 32 j x {Re,Im}
    const int by = blockIdx.y;          // k-tile: 64 rows of Ucol
    const int t  = threadIdx.x;
    const int r  = t >> 3;              // 0..31
    const int c8 = (t & 7) * 8;         // 0..56

    #pragma unroll
    for (int kk = 0; kk < 64; kk += 32) {
        *(f16x8*)&tile[kk + r][c8] =
            *(const f16x8*)(Ucol + (size_t)(by * 64 + kk + r) * 2048 + bx * 64 + c8);
    }
    __syncthreads();
    {
        f16x8 ore, oim;
        #pragma unroll
        for (int u = 0; u < 8; ++u) {
            ore[u] = tile[c8 + u][2 * r];
            oim[u] = tile[c8 + u][2 * r + 1];
        }
        const int j = bx * 32 + r;
        *(f16x8*)(Bil + (size_t)j * 1024 + by * 64 + c8) = ore;
        *(f16x8*)(Bil + (size_t)(1024 + j) * 1024 + by * 64 + c8) = oim;
    }
}

// f16x8 frag read from a [rows][64] half-slot with chunk-XOR swizzle
__device__ __forceinline__ f16x8 ldsfrag(const _Float16* base, int hrow, int c) {
    return *(const f16x8*)(base + hrow * 64 + ((c ^ (hrow & 7)) << 3));
}

// ---------------- Main GEMM: 256-row x 128-j tile, BK=64, 8-phase ----------
// A = Xh (8192x1024). B = Bil split layout: Re rows [j0,j0+128),
// Im rows [1024+j0, 1024+j0+128). Each wave: 128 A-rows x 32 j, holding
// matched Re/Im accumulator pairs -> shfl-free coalesced epilogue.
#define NKT 16     // 1024 / 64

__global__ __launch_bounds__(512, 2)
void gemm_kernel(const _Float16* __restrict__ A, const _Float16* __restrict__ B,
                 const float* __restrict__ invs, float* __restrict__ out) {
    __shared__ _Float16 As[2][2][8192];   // [buf][M-half][128 rows x 64 k], 64 KB
    __shared__ _Float16 Bs[2][2][8192];   // [buf][Re/Im][128 rows x 64 k], 64 KB
    const int t    = threadIdx.x;
    const int lane = t & 63;
    const int wid  = t >> 6;      // 0..7
    const int wm   = wid >> 2;    // 0..1 : M-half (128 rows)
    const int wn   = wid & 3;     // 0..3 : j-slice (32 j)

    // T1: XCD x gets m-panels 4x..4x+3, all 8 j-panels
    const int bid   = blockIdx.x;          // 256 blocks
    const int local = bid >> 3;            // 0..31
    const int m0 = ((bid & 7) * 4 + (local & 3)) * 256;
    const int j0 = (local >> 2) * 128;     // 8 j-panels of 128

    const _Float16* Ag0 = A + (size_t)m0 * 1024;            // A rows m0..+127
    const _Float16* Ag1 = A + (size_t)(m0 + 128) * 1024;    // A rows +128..+255
    const _Float16* Bg0 = B + (size_t)j0 * 1024;            // Re rows j0..+127
    const _Float16* Bg1 = B + (size_t)(1024 + j0) * 1024;   // Im rows

    const int srow = t >> 3;                       // 0..63 (and +64)
    const int sgc  = ((t & 7) ^ (srow & 7)) * 8;   // swizzled source chunk, elems
    #define STAGE_HALF(dst, gbase, kt)                                              \
        do {                                                                        \
            __builtin_amdgcn_global_load_lds(                                       \
                (const __attribute__((address_space(1))) void*)                     \
                    ((gbase) + (size_t)srow * 1024 + (kt) * 64 + sgc),              \
                (__attribute__((address_space(3))) void*)((dst) + t * 8), 16, 0, 0);\
            __builtin_amdgcn_global_load_lds(                                       \
                (const __attribute__((address_space(1))) void*)                     \
                    ((gbase) + (size_t)(64 + srow) * 1024 + (kt) * 64 + sgc),       \
                (__attribute__((address_space(3))) void*)((dst) + 4096 + t * 8),    \
                16, 0, 0);                                                          \
        } while (0)

    // acc[mf][0..1] = Re j-tiles, acc[mf][2..3] = Im j-tiles (same j-slice)
    f32x4 acc[8][4];
    const f32x4 zero = {0.f, 0.f, 0.f, 0.f};
    #pragma unroll
    for (int i = 0; i < 8; ++i)
        #pragma unroll
        for (int j = 0; j < 4; ++j) acc[i][j] = zero;

    const int fr = lane & 15;       // frag row within 16
    const int ch = lane >> 4;       // 16B chunk within 32-k sub-tile
    const int brow = wn * 32;       // wave's B-row base (within each half)

    // ---- prologue: tile 0 fully + A-half0 of tile 1; wait tile 0 only ----
    STAGE_HALF(&As[0][0][0], Ag0, 0);
    STAGE_HALF(&As[0][1][0], Ag1, 0);
    STAGE_HALF(&Bs[0][0][0], Bg0, 0);
    STAGE_HALF(&Bs[0][1][0], Bg1, 0);
    STAGE_HALF(&As[1][0][0], Ag0, 1);
    asm volatile("s_waitcnt vmcnt(2)" ::: "memory");
    __builtin_amdgcn_s_barrier();
    __builtin_amdgcn_sched_barrier(0);

    for (int tk = 0; tk < NKT; ++tk) {
        const int buf = tk & 1, nbuf = buf ^ 1;
        const _Float16* Ab   = &As[buf][wm][0];
        const _Float16* BbRe = &Bs[buf][0][0];
        const _Float16* BbIm = &Bs[buf][1][0];

        f16x8 afl[4][2], afh[4][2], bfa[2][2], bfb[2][2];

        // ---- phase 0: read afl + bfa(Re); stage A-half1(t+1) ----
        #pragma unroll
        for (int m = 0; m < 4; ++m)
            #pragma unroll
            for (int ks = 0; ks < 2; ++ks)
                afl[m][ks] = ldsfrag(Ab, m * 16 + fr, ks * 4 + ch);
        #pragma unroll
        for (int n = 0; n < 2; ++n)
            #pragma unroll
            for (int ks = 0; ks < 2; ++ks)
                bfa[n][ks] = ldsfrag(BbRe, brow + n * 16 + fr, ks * 4 + ch);
        if (tk + 1 < NKT) STAGE_HALF(&As[nbuf][1][0], Ag1, tk + 1);
        __builtin_amdgcn_s_barrier();
        asm volatile("s_waitcnt lgkmcnt(0)" ::: "memory");
        __builtin_amdgcn_sched_barrier(0);
        __builtin_amdgcn_s_setprio(1);
        #pragma unroll
        for (int m = 0; m < 4; ++m)
            #pragma unroll
            for (int n = 0; n < 2; ++n)
                #pragma unroll
                for (int ks = 0; ks < 2; ++ks)
                    acc[m][n] = __builtin_amdgcn_mfma_f32_16x16x32_f16(
                        afl[m][ks], bfa[n][ks], acc[m][n], 0, 0, 0);
        __builtin_amdgcn_s_setprio(0);
        __builtin_amdgcn_s_barrier();
        __builtin_amdgcn_sched_barrier(0);

        // ---- phase 1: read bfb(Im); stage B-Re(t+1) ----
        #pragma unroll
        for (int n = 0; n < 2; ++n)
            #pragma unroll
            for (int ks = 0; ks < 2; ++ks)
                bfb[n][ks] = ldsfrag(BbIm, brow + n * 16 + fr, ks * 4 + ch);
        if (tk + 1 < NKT) STAGE_HALF(&Bs[nbuf][0][0], Bg0, tk + 1);
        __builtin_amdgcn_s_barrier();
        asm volatile("s_waitcnt lgkmcnt(0)" ::: "memory");
        __builtin_amdgcn_sched_barrier(0);
        __builtin_amdgcn_s_setprio(1);
        #pragma unroll
        for (int m = 0; m < 4; ++m)
            #pragma unroll
            for (int n = 0; n < 2; ++n)
                #pragma unroll
                for (int ks = 0; ks < 2; ++ks)
                    acc[m][2 + n] = __builtin_amdgcn_mfma_f32_16x16x32_f16(
                        afl[m][ks], bfb[n][ks], acc[m][2 + n], 0, 0, 0);
        __builtin_amdgcn_s_setprio(0);
        __builtin_amdgcn_s_barrier();
        __builtin_amdgcn_sched_barrier(0);

        // ---- phase 2: read afh; stage B-Im(t+1) ----
        #pragma unroll
        for (int m = 0; m < 4; ++m)
            #pragma unroll
            for (int ks = 0; ks < 2; ++ks)
                afh[m][ks] = ldsfrag(Ab, 64 + m * 16 + fr, ks * 4 + ch);
        if (tk + 1 < NKT) STAGE_HALF(&Bs[nbuf][1][0], Bg1, tk + 1);
        __builtin_amdgcn_s_barrier();
        asm volatile("s_waitcnt lgkmcnt(0)" ::: "memory");
        __builtin_amdgcn_sched_barrier(0);
        __builtin_amdgcn_s_setprio(1);
        #pragma unroll
        for (int m = 0; m < 4; ++m)
            #pragma unroll
            for (int n = 0; n < 2; ++n)
                #pragma unroll
                for (int ks = 0; ks < 2; ++ks)
                    acc[4 + m][n] = __builtin_amdgcn_mfma_f32_16x16x32_f16(
                        afh[m][ks], bfa[n][ks], acc[4 + m][n], 0, 0, 0);
        __builtin_amdgcn_s_setprio(0);
        __builtin_amdgcn_s_barrier();
        __builtin_amdgcn_sched_barrier(0);

        // ---- phase 3: stage A-half0(t+2) into As[buf][0] (dead since p2) ----
        if (tk + 2 < NKT) STAGE_HALF(&As[buf][0][0], Ag0, tk + 2);
        __builtin_amdgcn_s_barrier();
        asm volatile("s_waitcnt lgkmcnt(0)" ::: "memory");
        __builtin_amdgcn_sched_barrier(0);
        __builtin_amdgcn_s_setprio(1);
        #pragma unroll
        for (int m = 0; m < 4; ++m)
            #pragma unroll
            for (int n = 0; n < 2; ++n)
                #pragma unroll
                for (int ks = 0; ks < 2; ++ks)
                    acc[4 + m][2 + n] = __builtin_amdgcn_mfma_f32_16x16x32_f16(
                        afh[m][ks], bfb[n][ks], acc[4 + m][2 + n], 0, 0, 0);
        __builtin_amdgcn_s_setprio(0);
        // boundary: tile t+1 ready when only A0(t+2)'s 2 loads remain in flight
        if (tk + 1 < NKT) {
            if (tk + 2 < NKT) asm volatile("s_waitcnt vmcnt(2)" ::: "memory");
            else              asm volatile("s_waitcnt vmcnt(0)" ::: "memory");
            __builtin_amdgcn_s_barrier();
            __builtin_amdgcn_sched_barrier(0);
        }
    }
    #undef STAGE_HALF

    // ---- epilogue: shfl-free. row = m0+wm*128+mf*16+(lane>>4)*4+r ;
    //      j = j0 + wn*32 + nf*16 + (lane&15). All 64 lanes store. ----
    const int colf = lane & 15;
    const int rowf = (lane >> 4) * 4;
    #pragma unroll
    for (int mf = 0; mf < 8; ++mf) {
        #pragma unroll
        for (int nf = 0; nf < 2; ++nf) {
            const int j = j0 + wn * 32 + nf * 16 + colf;
            #pragma unroll
            for (int r = 0; r < 4; ++r) {
                const int row = m0 + wm * 128 + mf * 16 + rowf + r;
                float re = acc[mf][nf][r];
                float im = acc[mf][2 + nf][r];
                float p = fminf((re * re + im * im) * invs[row], 1.0f);
                out[(size_t)row * DIM + j] = p;
            }
        }
    }
}

extern "C" void kernel_launch(void* const* d_in, const int* in_sizes, int n_in,
                              void* d_out, int out_size, void* d_ws, size_t ws_size,
                              hipStream_t stream) {
    const float* x = (const float*)d_in[0];     // (8192,1,32,32) fp32
    const float* w = (const float*)d_in[1];     // (16,10,3) fp32
    float* out = (float*)d_out;                 // (8192,1,32,32) fp32

    char* ws = (char*)d_ws;
    float*     gates = (float*)(ws + WS_GATES);
    int*       iperm = (int*)(ws + WS_IPERM);
    float*     invs  = (float*)(ws + WS_INVS);
    _Float16*  Xh    = (_Float16*)(ws + WS_XH);
    _Float16*  Bil   = (_Float16*)(ws + WS_BIL);
    // Ucol scratch lives in d_out (4 MB of its 32 MB); consumed by transpose
    // before gemm overwrites every element of d_out.
    _Float16*  Ucol  = (_Float16*)d_out;

    prep_kernel<<<1, 1024, 0, stream>>>(w, gates, iperm);
    fused_sim_kernel<<<3072, 256, 0, stream>>>(gates, iperm, Ucol, x, Xh, invs);
    transpose_kernel<<<dim3(32, 16), 256, 0, stream>>>(Ucol, Bil);
    gemm_kernel<<<256, 512, 0, stream>>>(Xh, Bil, invs, out);
}

// Round 16
// 98.654 us; speedup vs baseline: 1.5577x; 1.0014x over previous
//
#include <hip/hip_runtime.h>
#include <math.h>

#define NW     10
#define DIM    1024
#define QDEPTH 16

typedef __attribute__((ext_vector_type(8))) _Float16 f16x8;
typedef __attribute__((ext_vector_type(4))) _Float16 f16x4;
typedef __attribute__((ext_vector_type(2))) _Float16 f16x2;
typedef __attribute__((ext_vector_type(4))) float    f32x4;
typedef __attribute__((ext_vector_type(2))) float    f32x2;

// ---------------- ws layout ----------------
#define WS_GATES 0
#define WS_IPERM 8192
#define WS_INVS  81920
#define WS_XH    (1u << 20)     // 16 MB
#define WS_BIL   (17u << 20)    // 4 MB  (rows 0..1023 = Re U, 1024..2047 = Im U)
// d_out scratch: Ucol @0 (4 MB), consumed by transpose before gemm overwrites.

// slot hash: strictly increasing => bijective; max 1023+63+3 = 1089 < DIM+72.
// Spreads stride-16/32/64/256 access over 16 bank-pairs (gather-proof), and
// keeps all quad passes conflict-free (derived per pass).
#define SLOT(i) ((i) + ((i) >> 4) + ((i) >> 8))
#define STDIM   (DIM + 72)

// Packed complex gate: f32x2 elementwise FMAs lower to v_pk_fma_f32.
__device__ __forceinline__ void gate2(const float* __restrict__ g, f32x2& p0, f32x2& p1) {
    f32x2 s0; s0.x = -p0.y; s0.y = p0.x;   // i*p0
    f32x2 s1; s1.x = -p1.y; s1.y = p1.x;   // i*p1
    f32x2 n0 = g[0]*p0 + g[1]*s0 + g[2]*p1 + g[3]*s1;
    f32x2 n1 = g[4]*p0 + g[5]*s0 + g[6]*p1 + g[7]*s1;
    p0 = n0; p1 = n1;
}

__global__ __launch_bounds__(1024)
void prep_kernel(const float* __restrict__ w, float* __restrict__ gates,
                 int* __restrict__ iperm) {
    int t = threadIdx.x;
    const float PI = 3.14159265358979323846f;
    if (t < QDEPTH * NW) {
        // Rot(phi,theta,omega) = RZ(omega) RY(theta) RZ(phi); angles = tanh(w)*pi
        float phi   = tanhf(w[t*3 + 0]) * PI;
        float theta = tanhf(w[t*3 + 1]) * PI;
        float omega = tanhf(w[t*3 + 2]) * PI;
        float ch = cosf(theta * 0.5f), sh = sinf(theta * 0.5f);
        float ap = (phi + omega) * 0.5f;
        float am = (phi - omega) * 0.5f;
        float* g = gates + t * 8;
        g[0] =  cosf(ap) * ch;  g[1] = -sinf(ap) * ch;   // m00
        g[2] = -cosf(am) * sh;  g[3] = -sinf(am) * sh;   // m01
        g[4] =  cosf(am) * sh;  g[5] = -sinf(am) * sh;   // m10
        g[6] =  cosf(ap) * ch;  g[7] =  sinf(ap) * ch;   // m11
    }
    // Forward CNOT-block gather, PRE-SLOTTED: iperm[l][v] = SLOT(G_l(v)).
    int v = t;
    for (int l = 0; l < QDEPTH; ++l) {
        int r = (l % (NW - 1)) + 1;
        int u = v;
        for (int wq = NW - 1; wq >= 0; --wq) {
            int bc = 9 - wq;
            int bt = 9 - ((wq + r) % NW);
            u ^= ((u >> bc) & 1) << bt;
        }
        iperm[l * DIM + v] = SLOT(u);
    }
}

// Fused: 3072 blocks.
//   bid < 1024        : 16-layer column sim -> Ucol row bid
//   bid in [1024,3072): normcast for batch rows 4*(bid-1024)..+3
// Ping-pong state: b=8 session gathers st[p], writes canonical st[p^1]
// (no WAR -> no mid barrier; 2 barriers/layer). Quad passes (b=6,4,2,0)
// are wave-local in st[p^1] (every quad slot has i[9:8]=t[7:6]) -> lgkm only.
__global__ __launch_bounds__(256)
void fused_sim_kernel(const float* __restrict__ gates, const int* __restrict__ iperm,
                      _Float16* __restrict__ Ucol,
                      const float* __restrict__ x, _Float16* __restrict__ Xh,
                      float* __restrict__ invs) {
    __shared__ f32x2 st[2][STDIM];
    const int bid = blockIdx.x;
    const int t   = threadIdx.x;

    if (bid >= 1024) {
        // ---------------- normcast: 4 rows per block, 1 wave per row --------
        const int b = (bid - 1024) * 4 + (t >> 6);
        const int l = t & 63;
        const float4* xr = (const float4*)(x + (size_t)b * DIM);
        float4 v[4];
        float ss = 0.f;
        #pragma unroll
        for (int c = 0; c < 4; ++c) {
            v[c] = xr[l + c * 64];
            ss += v[c].x*v[c].x + v[c].y*v[c].y + v[c].z*v[c].z + v[c].w*v[c].w;
        }
        #pragma unroll
        for (int o = 32; o >= 1; o >>= 1) ss += __shfl_down(ss, o, 64);
        ss = __shfl(ss, 0, 64);
        if (l == 0) invs[b] = 1024.0f / ss;
        f16x4* xo = (f16x4*)(Xh + (size_t)b * DIM);
        #pragma unroll
        for (int c = 0; c < 4; ++c) {
            f16x4 h;
            h[0] = (_Float16)v[c].x; h[1] = (_Float16)v[c].y;
            h[2] = (_Float16)v[c].z; h[3] = (_Float16)v[c].w;
            xo[l + c * 64] = h;
        }
        return;
    }

    // ---------------- 16-layer column sim ----------------
    const int v = bid;

    int s4[4];
    #pragma unroll
    for (int k = 0; k < 4; ++k) s4[k] = SLOT(t + k * 256);
    int sq[4][4];
    #pragma unroll
    for (int pp = 0; pp < 4; ++pp) {
        const int b = 2 * pp;
        const int low = t & ((1 << b) - 1);
        const int i00 = ((t >> b) << (b + 2)) | low;
        sq[pp][0] = SLOT(i00);
        sq[pp][1] = SLOT(i00 | (1 << b));
        sq[pp][2] = SLOT(i00 | (2 << b));
        sq[pp][3] = SLOT(i00 | (3 << b));
    }

    #pragma unroll
    for (int k = 0; k < 4; ++k) {
        int i = t + k * 256;
        f32x2 e; e.x = (i == v) ? 1.f : 0.f; e.y = 0.f;
        st[0][s4[k]] = e;
    }
    __syncthreads();

    // pre-slotted perm indices for the NEXT layer's gather (prefetched)
    int pg0 = 0, pg1 = 0, pg2 = 0, pg3 = 0;
    int p = 0;   // state lives in st[p] (canonical layout)

    for (int l = 0; l < QDEPTH; ++l) {
        const float* gl = gates + l * NW * 8;
        const f32x2* src = st[p];
        f32x2*       dst = st[p ^ 1];

        // ---- barrier: all waves' quad writes to st[p] visible (l>0).
        if (l) __syncthreads();

        // ---- b=8 session (wires 0,1): gather perm l-1 from src ----
        f32x2 a00, a01, a10, a11;
        if (l == 0) {
            a00 = src[s4[0]]; a01 = src[s4[1]]; a10 = src[s4[2]]; a11 = src[s4[3]];
        } else {
            a00 = src[pg0]; a01 = src[pg1]; a10 = src[pg2]; a11 = src[pg3];
        }
        // prefetch pre-slotted perm row l (used at layer l+1 / final output)
        {
            const int* ipn = iperm + l * DIM;
            pg0 = ipn[t]; pg1 = ipn[t + 256]; pg2 = ipn[t + 512]; pg3 = ipn[t + 768];
        }
        gate2(gl + 0, a00, a10);   // wire 0 (bit 9)
        gate2(gl + 0, a01, a11);
        gate2(gl + 8, a00, a01);   // wire 1 (bit 8)
        gate2(gl + 8, a10, a11);
        // write canonical into dst: no WAR with src reads -> no barrier here
        dst[s4[0]] = a00; dst[s4[1]] = a01; dst[s4[2]] = a10; dst[s4[3]] = a11;
        __syncthreads();           // cross-wave canonical scatter visible

        // ---- quad passes b = 6,4,2,0 in dst: wave-local, lgkm only ----
        #pragma unroll
        for (int pp = 3; pp >= 0; --pp) {
            const int b = 2 * pp;
            const float* gh = gl + (8 - b) * 8;   // gate on bit b+1 (wire 8-b)
            const float* gm = gl + (9 - b) * 8;   // gate on bit b   (wire 9-b)
            f32x2 c00 = dst[sq[pp][0]], c01 = dst[sq[pp][1]];
            f32x2 c10 = dst[sq[pp][2]], c11 = dst[sq[pp][3]];
            gate2(gh, c00, c10);
            gate2(gh, c01, c11);
            gate2(gm, c00, c01);
            gate2(gm, c10, c11);
            dst[sq[pp][0]] = c00; dst[sq[pp][1]] = c01;
            dst[sq[pp][2]] = c10; dst[sq[pp][3]] = c11;
            asm volatile("s_waitcnt lgkmcnt(0)" ::: "memory");
            __builtin_amdgcn_sched_barrier(0);
        }
        p ^= 1;   // state now in st[p]
    }

    // ---- output with fused final perm (pre-slotted row 15 in pg*) ----
    __syncthreads();   // all waves' last quad writes visible
    const f32x2* fin = st[p];
    _Float16* col = Ucol + (size_t)v * 2048;
    {
        f32x2 a0 = fin[pg0], a1 = fin[pg1], a2 = fin[pg2], a3 = fin[pg3];
        f16x2 p0, p1, p2, p3;
        p0[0] = (_Float16)a0.x; p0[1] = (_Float16)a0.y;
        p1[0] = (_Float16)a1.x; p1[1] = (_Float16)a1.y;
        p2[0] = (_Float16)a2.x; p2[1] = (_Float16)a2.y;
        p3[0] = (_Float16)a3.x; p3[1] = (_Float16)a3.y;
        *(f16x2*)(col + 2 * t)         = p0;
        *(f16x2*)(col + 2 * (t + 256)) = p1;
        *(f16x2*)(col + 2 * (t + 512)) = p2;
        *(f16x2*)(col + 2 * (t + 768)) = p3;
    }
}

// Split-layout transpose: Bil[j][k] = Ucol[k][2j] (Re), Bil[1024+j][k] = Ucol[k][2j+1].
__global__ __launch_bounds__(256)
void transpose_kernel(const _Float16* __restrict__ Ucol, _Float16* __restrict__ Bil) {
    __shared__ _Float16 tile[64][72];
    const int bx = blockIdx.x;          // c-tile: 64 cols of Ucol = 32 j x {Re,Im}
    const int by = blockIdx.y;          // k-tile: 64 rows of Ucol
    const int t  = threadIdx.x;
    const int r  = t >> 3;              // 0..31
    const int c8 = (t & 7) * 8;         // 0..56

    #pragma unroll
    for (int kk = 0; kk < 64; kk += 32) {
        *(f16x8*)&tile[kk + r][c8] =
            *(const f16x8*)(Ucol + (size_t)(by * 64 + kk + r) * 2048 + bx * 64 + c8);
    }
    __syncthreads();
    {
        f16x8 ore, oim;
        #pragma unroll
        for (int u = 0; u < 8; ++u) {
            ore[u] = tile[c8 + u][2 * r];
            oim[u] = tile[c8 + u][2 * r + 1];
        }
        const int j = bx * 32 + r;
        *(f16x8*)(Bil + (size_t)j * 1024 + by * 64 + c8) = ore;
        *(f16x8*)(Bil + (size_t)(1024 + j) * 1024 + by * 64 + c8) = oim;
    }
}

// f16x8 frag read from a [rows][64] half-slot with chunk-XOR swizzle
__device__ __forceinline__ f16x8 ldsfrag(const _Float16* base, int hrow, int c) {
    return *(const f16x8*)(base + hrow * 64 + ((c ^ (hrow & 7)) << 3));
}

// ---------------- Main GEMM: 256-row x 128-j tile, BK=64, 8-phase ----------
// A = Xh (8192x1024). B = Bil split layout: Re rows [j0,j0+128),
// Im rows [1024+j0, 1024+j0+128). Each wave: 128 A-rows x 32 j, holding
// matched Re/Im accumulator pairs -> shfl-free coalesced epilogue.
#define NKT 16     // 1024 / 64

__global__ __launch_bounds__(512, 2)
void gemm_kernel(const _Float16* __restrict__ A, const _Float16* __restrict__ B,
                 const float* __restrict__ invs, float* __restrict__ out) {
    __shared__ _Float16 As[2][2][8192];   // [buf][M-half][128 rows x 64 k], 64 KB
    __shared__ _Float16 Bs[2][2][8192];   // [buf][Re/Im][128 rows x 64 k], 64 KB
    const int t    = threadIdx.x;
    const int lane = t & 63;
    const int wid  = t >> 6;      // 0..7
    const int wm   = wid >> 2;    // 0..1 : M-half (128 rows)
    const int wn   = wid & 3;     // 0..3 : j-slice (32 j)

    // T1: XCD x gets m-panels 4x..4x+3, all 8 j-panels
    const int bid   = blockIdx.x;          // 256 blocks
    const int local = bid >> 3;            // 0..31
    const int m0 = ((bid & 7) * 4 + (local & 3)) * 256;
    const int j0 = (local >> 2) * 128;     // 8 j-panels of 128

    const _Float16* Ag0 = A + (size_t)m0 * 1024;            // A rows m0..+127
    const _Float16* Ag1 = A + (size_t)(m0 + 128) * 1024;    // A rows +128..+255
    const _Float16* Bg0 = B + (size_t)j0 * 1024;            // Re rows j0..+127
    const _Float16* Bg1 = B + (size_t)(1024 + j0) * 1024;   // Im rows

    const int srow = t >> 3;                       // 0..63 (and +64)
    const int sgc  = ((t & 7) ^ (srow & 7)) * 8;   // swizzled source chunk, elems
    #define STAGE_HALF(dst, gbase, kt)                                              \
        do {                                                                        \
            __builtin_amdgcn_global_load_lds(                                       \
                (const __attribute__((address_space(1))) void*)                     \
                    ((gbase) + (size_t)srow * 1024 + (kt) * 64 + sgc),              \
                (__attribute__((address_space(3))) void*)((dst) + t * 8), 16, 0, 0);\
            __builtin_amdgcn_global_load_lds(                                       \
                (const __attribute__((address_space(1))) void*)                     \
                    ((gbase) + (size_t)(64 + srow) * 1024 + (kt) * 64 + sgc),       \
                (__attribute__((address_space(3))) void*)((dst) + 4096 + t * 8),    \
                16, 0, 0);                                                          \
        } while (0)

    // acc[mf][0..1] = Re j-tiles, acc[mf][2..3] = Im j-tiles (same j-slice)
    f32x4 acc[8][4];
    const f32x4 zero = {0.f, 0.f, 0.f, 0.f};
    #pragma unroll
    for (int i = 0; i < 8; ++i)
        #pragma unroll
        for (int j = 0; j < 4; ++j) acc[i][j] = zero;

    const int fr = lane & 15;       // frag row within 16
    const int ch = lane >> 4;       // 16B chunk within 32-k sub-tile
    const int brow = wn * 32;       // wave's B-row base (within each half)

    // ---- prologue: tile 0 fully + A-half0 of tile 1; wait tile 0 only ----
    STAGE_HALF(&As[0][0][0], Ag0, 0);
    STAGE_HALF(&As[0][1][0], Ag1, 0);
    STAGE_HALF(&Bs[0][0][0], Bg0, 0);
    STAGE_HALF(&Bs[0][1][0], Bg1, 0);
    STAGE_HALF(&As[1][0][0], Ag0, 1);
    asm volatile("s_waitcnt vmcnt(2)" ::: "memory");
    __builtin_amdgcn_s_barrier();
    __builtin_amdgcn_sched_barrier(0);

    for (int tk = 0; tk < NKT; ++tk) {
        const int buf = tk & 1, nbuf = buf ^ 1;
        const _Float16* Ab   = &As[buf][wm][0];
        const _Float16* BbRe = &Bs[buf][0][0];
        const _Float16* BbIm = &Bs[buf][1][0];

        f16x8 afl[4][2], afh[4][2], bfa[2][2], bfb[2][2];

        // ---- phase 0: read afl + bfa(Re); stage A-half1(t+1) ----
        #pragma unroll
        for (int m = 0; m < 4; ++m)
            #pragma unroll
            for (int ks = 0; ks < 2; ++ks)
                afl[m][ks] = ldsfrag(Ab, m * 16 + fr, ks * 4 + ch);
        #pragma unroll
        for (int n = 0; n < 2; ++n)
            #pragma unroll
            for (int ks = 0; ks < 2; ++ks)
                bfa[n][ks] = ldsfrag(BbRe, brow + n * 16 + fr, ks * 4 + ch);
        if (tk + 1 < NKT) STAGE_HALF(&As[nbuf][1][0], Ag1, tk + 1);
        __builtin_amdgcn_s_barrier();
        asm volatile("s_waitcnt lgkmcnt(0)" ::: "memory");
        __builtin_amdgcn_sched_barrier(0);
        __builtin_amdgcn_s_setprio(1);
        #pragma unroll
        for (int m = 0; m < 4; ++m)
            #pragma unroll
            for (int n = 0; n < 2; ++n)
                #pragma unroll
                for (int ks = 0; ks < 2; ++ks)
                    acc[m][n] = __builtin_amdgcn_mfma_f32_16x16x32_f16(
                        afl[m][ks], bfa[n][ks], acc[m][n], 0, 0, 0);
        __builtin_amdgcn_s_setprio(0);
        __builtin_amdgcn_s_barrier();
        __builtin_amdgcn_sched_barrier(0);

        // ---- phase 1: read bfb(Im); stage B-Re(t+1) ----
        #pragma unroll
        for (int n = 0; n < 2; ++n)
            #pragma unroll
            for (int ks = 0; ks < 2; ++ks)
                bfb[n][ks] = ldsfrag(BbIm, brow + n * 16 + fr, ks * 4 + ch);
        if (tk + 1 < NKT) STAGE_HALF(&Bs[nbuf][0][0], Bg0, tk + 1);
        __builtin_amdgcn_s_barrier();
        asm volatile("s_waitcnt lgkmcnt(0)" ::: "memory");
        __builtin_amdgcn_sched_barrier(0);
        __builtin_amdgcn_s_setprio(1);
        #pragma unroll
        for (int m = 0; m < 4; ++m)
            #pragma unroll
            for (int n = 0; n < 2; ++n)
                #pragma unroll
                for (int ks = 0; ks < 2; ++ks)
                    acc[m][2 + n] = __builtin_amdgcn_mfma_f32_16x16x32_f16(
                        afl[m][ks], bfb[n][ks], acc[m][2 + n], 0, 0, 0);
        __builtin_amdgcn_s_setprio(0);
        __builtin_amdgcn_s_barrier();
        __builtin_amdgcn_sched_barrier(0);

        // ---- phase 2: read afh; stage B-Im(t+1) ----
        #pragma unroll
        for (int m = 0; m < 4; ++m)
            #pragma unroll
            for (int ks = 0; ks < 2; ++ks)
                afh[m][ks] = ldsfrag(Ab, 64 + m * 16 + fr, ks * 4 + ch);
        if (tk + 1 < NKT) STAGE_HALF(&Bs[nbuf][1][0], Bg1, tk + 1);
        __builtin_amdgcn_s_barrier();
        asm volatile("s_waitcnt lgkmcnt(0)" ::: "memory");
        __builtin_amdgcn_sched_barrier(0);
        __builtin_amdgcn_s_setprio(1);
        #pragma unroll
        for (int m = 0; m < 4; ++m)
            #pragma unroll
            for (int n = 0; n < 2; ++n)
                #pragma unroll
                for (int ks = 0; ks < 2; ++ks)
                    acc[4 + m][n] = __builtin_amdgcn_mfma_f32_16x16x32_f16(
                        afh[m][ks], bfa[n][ks], acc[4 + m][n], 0, 0, 0);
        __builtin_amdgcn_s_setprio(0);
        __builtin_amdgcn_s_barrier();
        __builtin_amdgcn_sched_barrier(0);

        // ---- phase 3: stage A-half0(t+2) into As[buf][0] (dead since p2) ----
        if (tk + 2 < NKT) STAGE_HALF(&As[buf][0][0], Ag0, tk + 2);
        __builtin_amdgcn_s_barrier();
        asm volatile("s_waitcnt lgkmcnt(0)" ::: "memory");
        __builtin_amdgcn_sched_barrier(0);
        __builtin_amdgcn_s_setprio(1);
        #pragma unroll
        for (int m = 0; m < 4; ++m)
            #pragma unroll
            for (int n = 0; n < 2; ++n)
                #pragma unroll
                for (int ks = 0; ks < 2; ++ks)
                    acc[4 + m][2 + n] = __builtin_amdgcn_mfma_f32_16x16x32_f16(
                        afh[m][ks], bfb[n][ks], acc[4 + m][2 + n], 0, 0, 0);
        __builtin_amdgcn_s_setprio(0);
        // boundary: tile t+1 ready when only A0(t+2)'s 2 loads remain in flight
        if (tk + 1 < NKT) {
            if (tk + 2 < NKT) asm volatile("s_waitcnt vmcnt(2)" ::: "memory");
            else              asm volatile("s_waitcnt vmcnt(0)" ::: "memory");
            __builtin_amdgcn_s_barrier();
            __builtin_amdgcn_sched_barrier(0);
        }
    }
    #undef STAGE_HALF

    // ---- epilogue: shfl-free. row = m0+wm*128+mf*16+(lane>>4)*4+r ;
    //      j = j0 + wn*32 + nf*16 + (lane&15). All 64 lanes store. ----
    const int colf = lane & 15;
    const int rowf = (lane >> 4) * 4;
    #pragma unroll
    for (int mf = 0; mf < 8; ++mf) {
        #pragma unroll
        for (int nf = 0; nf < 2; ++nf) {
            const int j = j0 + wn * 32 + nf * 16 + colf;
            #pragma unroll
            for (int r = 0; r < 4; ++r) {
                const int row = m0 + wm * 128 + mf * 16 + rowf + r;
                float re = acc[mf][nf][r];
                float im = acc[mf][2 + nf][r];
                float p = fminf((re * re + im * im) * invs[row], 1.0f);
                out[(size_t)row * DIM + j] = p;
            }
        }
    }
}

extern "C" void kernel_launch(void* const* d_in, const int* in_sizes, int n_in,
                              void* d_out, int out_size, void* d_ws, size_t ws_size,
                              hipStream_t stream) {
    const float* x = (const float*)d_in[0];     // (8192,1,32,32) fp32
    const float* w = (const float*)d_in[1];     // (16,10,3) fp32
    float* out = (float*)d_out;                 // (8192,1,32,32) fp32

    char* ws = (char*)d_ws;
    float*     gates = (float*)(ws + WS_GATES);
    int*       iperm = (int*)(ws + WS_IPERM);
    float*     invs  = (float*)(ws + WS_INVS);
    _Float16*  Xh    = (_Float16*)(ws + WS_XH);
    _Float16*  Bil   = (_Float16*)(ws + WS_BIL);
    // Ucol scratch lives in d_out (4 MB of its 32 MB); consumed by transpose
    // before gemm overwrites every element of d_out.
    _Float16*  Ucol  = (_Float16*)d_out;

    prep_kernel<<<1, 1024, 0, stream>>>(w, gates, iperm);
    fused_sim_kernel<<<3072, 256, 0, stream>>>(gates, iperm, Ucol, x, Xh, invs);
    transpose_kernel<<<dim3(32, 16), 256, 0, stream>>>(Ucol, Bil);
    gemm_kernel<<<256, 512, 0, stream>>>(Xh, Bil, invs, out);
}

// Round 17
// 95.378 us; speedup vs baseline: 1.6112x; 1.0344x over previous
//
#include <hip/hip_runtime.h>
#include <math.h>

#define NW     10
#define DIM    1024
#define QDEPTH 16

typedef __attribute__((ext_vector_type(8))) _Float16 f16x8;
typedef __attribute__((ext_vector_type(4))) _Float16 f16x4;
typedef __attribute__((ext_vector_type(2))) _Float16 f16x2;
typedef __attribute__((ext_vector_type(4))) float    f32x4;
typedef __attribute__((ext_vector_type(2))) float    f32x2;

// ---------------- ws layout ----------------
#define WS_GATES 0
#define WS_IPERM 8192
#define WS_INVS  81920
#define WS_XH    (1u << 20)     // 16 MB
#define WS_BIL   (17u << 20)    // 4 MB  (rows 0..1023 = Re U, 1024..2047 = Im U)
// d_out scratch: Ucol @0 (4 MB), consumed by transpose before gemm overwrites.

// slot hash: strictly increasing => bijective; max 1023+63+3 = 1089 < DIM+72.
#define SLOT(i) ((i) + ((i) >> 4) + ((i) >> 8))
#define STDIM   (DIM + 72)

// Packed complex gate: f32x2 elementwise FMAs lower to v_pk_fma_f32.
__device__ __forceinline__ void gate2(const float* __restrict__ g, f32x2& p0, f32x2& p1) {
    f32x2 s0; s0.x = -p0.y; s0.y = p0.x;   // i*p0
    f32x2 s1; s1.x = -p1.y; s1.y = p1.x;   // i*p1
    f32x2 n0 = g[0]*p0 + g[1]*s0 + g[2]*p1 + g[3]*s1;
    f32x2 n1 = g[4]*p0 + g[5]*s0 + g[6]*p1 + g[7]*s1;
    p0 = n0; p1 = n1;
}

__global__ __launch_bounds__(1024)
void prep_kernel(const float* __restrict__ w, float* __restrict__ gates,
                 int* __restrict__ iperm) {
    int t = threadIdx.x;
    const float PI = 3.14159265358979323846f;
    if (t < QDEPTH * NW) {
        // Rot(phi,theta,omega) = RZ(omega) RY(theta) RZ(phi); angles = tanh(w)*pi
        float phi   = tanhf(w[t*3 + 0]) * PI;
        float theta = tanhf(w[t*3 + 1]) * PI;
        float omega = tanhf(w[t*3 + 2]) * PI;
        float ch = cosf(theta * 0.5f), sh = sinf(theta * 0.5f);
        float ap = (phi + omega) * 0.5f;
        float am = (phi - omega) * 0.5f;
        float* g = gates + t * 8;
        g[0] =  cosf(ap) * ch;  g[1] = -sinf(ap) * ch;   // m00
        g[2] = -cosf(am) * sh;  g[3] = -sinf(am) * sh;   // m01
        g[4] =  cosf(am) * sh;  g[5] = -sinf(am) * sh;   // m10
        g[6] =  cosf(ap) * ch;  g[7] =  sinf(ap) * ch;   // m11
    }
    // Forward CNOT-block gather, PRE-SLOTTED: iperm[l][v] = SLOT(G_l(v)).
    int v = t;
    for (int l = 0; l < QDEPTH; ++l) {
        int r = (l % (NW - 1)) + 1;
        int u = v;
        for (int wq = NW - 1; wq >= 0; --wq) {
            int bc = 9 - wq;
            int bt = 9 - ((wq + r) % NW);
            u ^= ((u >> bc) & 1) << bt;
        }
        iperm[l * DIM + v] = SLOT(u);
    }
}

// Fused: 3072 blocks.
//   bid < 1024        : 16-layer column sim -> Ucol row bid
//   bid in [1024,3072): normcast for batch rows 4*(bid-1024)..+3
// Ping-pong state; 2 barriers/layer; quad passes wave-local (lgkm only).
// Bank-conflict-free lane->quad maps (derived per pass, per 32-lane phase):
//   pp=3,2,0: canonical map already covers each s%16 residue exactly 2x.
//   pp=1 (b=2): canonical map had 4-way conflicts ((4k+(l&3)+(l>>2))%16);
//   remapped to bits[7:4]=l&15, bits[1:0]=l>>4 -> (4k+(l&15)+(l>>4))%16,
//   every residue exactly 2x per phase. Bijective within the wave's region
//   (i[9:8]=w), so ownership/barrier arguments are unchanged.
__global__ __launch_bounds__(256)
void fused_sim_kernel(const float* __restrict__ gates, const int* __restrict__ iperm,
                      _Float16* __restrict__ Ucol,
                      const float* __restrict__ x, _Float16* __restrict__ Xh,
                      float* __restrict__ invs) {
    __shared__ f32x2 st[2][STDIM];
    const int bid = blockIdx.x;
    const int t   = threadIdx.x;

    if (bid >= 1024) {
        // ---------------- normcast: 4 rows per block, 1 wave per row --------
        const int b = (bid - 1024) * 4 + (t >> 6);
        const int l = t & 63;
        const float4* xr = (const float4*)(x + (size_t)b * DIM);
        float4 v[4];
        float ss = 0.f;
        #pragma unroll
        for (int c = 0; c < 4; ++c) {
            v[c] = xr[l + c * 64];
            ss += v[c].x*v[c].x + v[c].y*v[c].y + v[c].z*v[c].z + v[c].w*v[c].w;
        }
        #pragma unroll
        for (int o = 32; o >= 1; o >>= 1) ss += __shfl_down(ss, o, 64);
        ss = __shfl(ss, 0, 64);
        if (l == 0) invs[b] = 1024.0f / ss;
        f16x4* xo = (f16x4*)(Xh + (size_t)b * DIM);
        #pragma unroll
        for (int c = 0; c < 4; ++c) {
            f16x4 h;
            h[0] = (_Float16)v[c].x; h[1] = (_Float16)v[c].y;
            h[2] = (_Float16)v[c].z; h[3] = (_Float16)v[c].w;
            xo[l + c * 64] = h;
        }
        return;
    }

    // ---------------- 16-layer column sim ----------------
    const int v = bid;
    const int w = t >> 6, l6 = t & 63;

    int s4[4];
    #pragma unroll
    for (int k = 0; k < 4; ++k) s4[k] = SLOT(t + k * 256);
    int sq[4][4];
    #pragma unroll
    for (int pp = 0; pp < 4; ++pp) {
        const int b = 2 * pp;
        int i00;
        if (pp == 1) {
            // conflict-free remap: bits[7:4]=l&15, bits[1:0]=l>>4
            i00 = (w << 8) | ((l6 & 15) << 4) | (l6 >> 4);
        } else {
            const int low = t & ((1 << b) - 1);
            i00 = ((t >> b) << (b + 2)) | low;
        }
        sq[pp][0] = SLOT(i00);
        sq[pp][1] = SLOT(i00 | (1 << b));
        sq[pp][2] = SLOT(i00 | (2 << b));
        sq[pp][3] = SLOT(i00 | (3 << b));
    }

    #pragma unroll
    for (int k = 0; k < 4; ++k) {
        int i = t + k * 256;
        f32x2 e; e.x = (i == v) ? 1.f : 0.f; e.y = 0.f;
        st[0][s4[k]] = e;
    }
    __syncthreads();

    // pre-slotted perm indices for the NEXT layer's gather (prefetched)
    int pg0 = 0, pg1 = 0, pg2 = 0, pg3 = 0;
    int p = 0;   // state lives in st[p] (canonical layout)

    for (int l = 0; l < QDEPTH; ++l) {
        const float* gl = gates + l * NW * 8;
        const f32x2* src = st[p];
        f32x2*       dst = st[p ^ 1];

        // ---- barrier: all waves' quad writes to st[p] visible (l>0).
        if (l) __syncthreads();

        // ---- b=8 session (wires 0,1): gather perm l-1 from src ----
        f32x2 a00, a01, a10, a11;
        if (l == 0) {
            a00 = src[s4[0]]; a01 = src[s4[1]]; a10 = src[s4[2]]; a11 = src[s4[3]];
        } else {
            a00 = src[pg0]; a01 = src[pg1]; a10 = src[pg2]; a11 = src[pg3];
        }
        // prefetch pre-slotted perm row l (used at layer l+1 / final output)
        {
            const int* ipn = iperm + l * DIM;
            pg0 = ipn[t]; pg1 = ipn[t + 256]; pg2 = ipn[t + 512]; pg3 = ipn[t + 768];
        }
        gate2(gl + 0, a00, a10);   // wire 0 (bit 9)
        gate2(gl + 0, a01, a11);
        gate2(gl + 8, a00, a01);   // wire 1 (bit 8)
        gate2(gl + 8, a10, a11);
        // write canonical into dst: no WAR with src reads -> no barrier here
        dst[s4[0]] = a00; dst[s4[1]] = a01; dst[s4[2]] = a10; dst[s4[3]] = a11;
        __syncthreads();           // cross-wave canonical scatter visible

        // ---- quad passes b = 6,4,2,0 in dst: wave-local, lgkm only ----
        #pragma unroll
        for (int pp = 3; pp >= 0; --pp) {
            const int b = 2 * pp;
            const float* gh = gl + (8 - b) * 8;   // gate on bit b+1 (wire 8-b)
            const float* gm = gl + (9 - b) * 8;   // gate on bit b   (wire 9-b)
            f32x2 c00 = dst[sq[pp][0]], c01 = dst[sq[pp][1]];
            f32x2 c10 = dst[sq[pp][2]], c11 = dst[sq[pp][3]];
            gate2(gh, c00, c10);
            gate2(gh, c01, c11);
            gate2(gm, c00, c01);
            gate2(gm, c10, c11);
            dst[sq[pp][0]] = c00; dst[sq[pp][1]] = c01;
            dst[sq[pp][2]] = c10; dst[sq[pp][3]] = c11;
            asm volatile("s_waitcnt lgkmcnt(0)" ::: "memory");
            __builtin_amdgcn_sched_barrier(0);
        }
        p ^= 1;   // state now in st[p]
    }

    // ---- output with fused final perm (pre-slotted row 15 in pg*) ----
    __syncthreads();   // all waves' last quad writes visible
    const f32x2* fin = st[p];
    _Float16* col = Ucol + (size_t)v * 2048;
    {
        f32x2 a0 = fin[pg0], a1 = fin[pg1], a2 = fin[pg2], a3 = fin[pg3];
        f16x2 p0, p1, p2, p3;
        p0[0] = (_Float16)a0.x; p0[1] = (_Float16)a0.y;
        p1[0] = (_Float16)a1.x; p1[1] = (_Float16)a1.y;
        p2[0] = (_Float16)a2.x; p2[1] = (_Float16)a2.y;
        p3[0] = (_Float16)a3.x; p3[1] = (_Float16)a3.y;
        *(f16x2*)(col + 2 * t)         = p0;
        *(f16x2*)(col + 2 * (t + 256)) = p1;
        *(f16x2*)(col + 2 * (t + 512)) = p2;
        *(f16x2*)(col + 2 * (t + 768)) = p3;
    }
}

// Split-layout transpose: Bil[j][k] = Ucol[k][2j] (Re), Bil[1024+j][k] = Ucol[k][2j+1].
__global__ __launch_bounds__(256)
void transpose_kernel(const _Float16* __restrict__ Ucol, _Float16* __restrict__ Bil) {
    __shared__ _Float16 tile[64][72];
    const int bx = blockIdx.x;          // c-tile: 64 cols of Ucol = 32 j x {Re,Im}
    const int by = blockIdx.y;          // k-tile: 64 rows of Ucol
    const int t  = threadIdx.x;
    const int r  = t >> 3;              // 0..31
    const int c8 = (t & 7) * 8;         // 0..56

    #pragma unroll
    for (int kk = 0; kk < 64; kk += 32) {
        *(f16x8*)&tile[kk + r][c8] =
            *(const f16x8*)(Ucol + (size_t)(by * 64 + kk + r) * 2048 + bx * 64 + c8);
    }
    __syncthreads();
    {
        f16x8 ore, oim;
        #pragma unroll
        for (int u = 0; u < 8; ++u) {
            ore[u] = tile[c8 + u][2 * r];
            oim[u] = tile[c8 + u][2 * r + 1];
        }
        const int j = bx * 32 + r;
        *(f16x8*)(Bil + (size_t)j * 1024 + by * 64 + c8) = ore;
        *(f16x8*)(Bil + (size_t)(1024 + j) * 1024 + by * 64 + c8) = oim;
    }
}

// f16x8 frag read from a [rows][64] half-slot with chunk-XOR swizzle
__device__ __forceinline__ f16x8 ldsfrag(const _Float16* base, int hrow, int c) {
    return *(const f16x8*)(base + hrow * 64 + ((c ^ (hrow & 7)) << 3));
}

// ---------------- Main GEMM: 256-row x 128-j tile, BK=64, 8-phase ----------
// A = Xh (8192x1024). B = Bil split layout: Re rows [j0,j0+128),
// Im rows [1024+j0, 1024+j0+128). Each wave: 128 A-rows x 32 j, holding
// matched Re/Im accumulator pairs -> shfl-free coalesced epilogue.
#define NKT 16     // 1024 / 64

__global__ __launch_bounds__(512, 2)
void gemm_kernel(const _Float16* __restrict__ A, const _Float16* __restrict__ B,
                 const float* __restrict__ invs, float* __restrict__ out) {
    __shared__ _Float16 As[2][2][8192];   // [buf][M-half][128 rows x 64 k], 64 KB
    __shared__ _Float16 Bs[2][2][8192];   // [buf][Re/Im][128 rows x 64 k], 64 KB
    const int t    = threadIdx.x;
    const int lane = t & 63;
    const int wid  = t >> 6;      // 0..7
    const int wm   = wid >> 2;    // 0..1 : M-half (128 rows)
    const int wn   = wid & 3;     // 0..3 : j-slice (32 j)

    // T1: XCD x gets m-panels 4x..4x+3, all 8 j-panels
    const int bid   = blockIdx.x;          // 256 blocks
    const int local = bid >> 3;            // 0..31
    const int m0 = ((bid & 7) * 4 + (local & 3)) * 256;
    const int j0 = (local >> 2) * 128;     // 8 j-panels of 128

    const _Float16* Ag0 = A + (size_t)m0 * 1024;            // A rows m0..+127
    const _Float16* Ag1 = A + (size_t)(m0 + 128) * 1024;    // A rows +128..+255
    const _Float16* Bg0 = B + (size_t)j0 * 1024;            // Re rows j0..+127
    const _Float16* Bg1 = B + (size_t)(1024 + j0) * 1024;   // Im rows

    const int srow = t >> 3;                       // 0..63 (and +64)
    const int sgc  = ((t & 7) ^ (srow & 7)) * 8;   // swizzled source chunk, elems
    #define STAGE_HALF(dst, gbase, kt)                                              \
        do {                                                                        \
            __builtin_amdgcn_global_load_lds(                                       \
                (const __attribute__((address_space(1))) void*)                     \
                    ((gbase) + (size_t)srow * 1024 + (kt) * 64 + sgc),              \
                (__attribute__((address_space(3))) void*)((dst) + t * 8), 16, 0, 0);\
            __builtin_amdgcn_global_load_lds(                                       \
                (const __attribute__((address_space(1))) void*)                     \
                    ((gbase) + (size_t)(64 + srow) * 1024 + (kt) * 64 + sgc),       \
                (__attribute__((address_space(3))) void*)((dst) + 4096 + t * 8),    \
                16, 0, 0);                                                          \
        } while (0)

    // acc[mf][0..1] = Re j-tiles, acc[mf][2..3] = Im j-tiles (same j-slice)
    f32x4 acc[8][4];
    const f32x4 zero = {0.f, 0.f, 0.f, 0.f};
    #pragma unroll
    for (int i = 0; i < 8; ++i)
        #pragma unroll
        for (int j = 0; j < 4; ++j) acc[i][j] = zero;

    const int fr = lane & 15;       // frag row within 16
    const int ch = lane >> 4;       // 16B chunk within 32-k sub-tile
    const int brow = wn * 32;       // wave's B-row base (within each half)

    // ---- prologue: tile 0 fully + A-half0 of tile 1; wait tile 0 only ----
    STAGE_HALF(&As[0][0][0], Ag0, 0);
    STAGE_HALF(&As[0][1][0], Ag1, 0);
    STAGE_HALF(&Bs[0][0][0], Bg0, 0);
    STAGE_HALF(&Bs[0][1][0], Bg1, 0);
    STAGE_HALF(&As[1][0][0], Ag0, 1);
    asm volatile("s_waitcnt vmcnt(2)" ::: "memory");
    __builtin_amdgcn_s_barrier();
    __builtin_amdgcn_sched_barrier(0);

    for (int tk = 0; tk < NKT; ++tk) {
        const int buf = tk & 1, nbuf = buf ^ 1;
        const _Float16* Ab   = &As[buf][wm][0];
        const _Float16* BbRe = &Bs[buf][0][0];
        const _Float16* BbIm = &Bs[buf][1][0];

        f16x8 afl[4][2], afh[4][2], bfa[2][2], bfb[2][2];

        // ---- phase 0: read afl + bfa(Re); stage A-half1(t+1) ----
        #pragma unroll
        for (int m = 0; m < 4; ++m)
            #pragma unroll
            for (int ks = 0; ks < 2; ++ks)
                afl[m][ks] = ldsfrag(Ab, m * 16 + fr, ks * 4 + ch);
        #pragma unroll
        for (int n = 0; n < 2; ++n)
            #pragma unroll
            for (int ks = 0; ks < 2; ++ks)
                bfa[n][ks] = ldsfrag(BbRe, brow + n * 16 + fr, ks * 4 + ch);
        if (tk + 1 < NKT) STAGE_HALF(&As[nbuf][1][0], Ag1, tk + 1);
        __builtin_amdgcn_s_barrier();
        asm volatile("s_waitcnt lgkmcnt(0)" ::: "memory");
        __builtin_amdgcn_sched_barrier(0);
        __builtin_amdgcn_s_setprio(1);
        #pragma unroll
        for (int m = 0; m < 4; ++m)
            #pragma unroll
            for (int n = 0; n < 2; ++n)
                #pragma unroll
                for (int ks = 0; ks < 2; ++ks)
                    acc[m][n] = __builtin_amdgcn_mfma_f32_16x16x32_f16(
                        afl[m][ks], bfa[n][ks], acc[m][n], 0, 0, 0);
        __builtin_amdgcn_s_setprio(0);
        __builtin_amdgcn_s_barrier();
        __builtin_amdgcn_sched_barrier(0);

        // ---- phase 1: read bfb(Im); stage B-Re(t+1) ----
        #pragma unroll
        for (int n = 0; n < 2; ++n)
            #pragma unroll
            for (int ks = 0; ks < 2; ++ks)
                bfb[n][ks] = ldsfrag(BbIm, brow + n * 16 + fr, ks * 4 + ch);
        if (tk + 1 < NKT) STAGE_HALF(&Bs[nbuf][0][0], Bg0, tk + 1);
        __builtin_amdgcn_s_barrier();
        asm volatile("s_waitcnt lgkmcnt(0)" ::: "memory");
        __builtin_amdgcn_sched_barrier(0);
        __builtin_amdgcn_s_setprio(1);
        #pragma unroll
        for (int m = 0; m < 4; ++m)
            #pragma unroll
            for (int n = 0; n < 2; ++n)
                #pragma unroll
                for (int ks = 0; ks < 2; ++ks)
                    acc[m][2 + n] = __builtin_amdgcn_mfma_f32_16x16x32_f16(
                        afl[m][ks], bfb[n][ks], acc[m][2 + n], 0, 0, 0);
        __builtin_amdgcn_s_setprio(0);
        __builtin_amdgcn_s_barrier();
        __builtin_amdgcn_sched_barrier(0);

        // ---- phase 2: read afh; stage B-Im(t+1) ----
        #pragma unroll
        for (int m = 0; m < 4; ++m)
            #pragma unroll
            for (int ks = 0; ks < 2; ++ks)
                afh[m][ks] = ldsfrag(Ab, 64 + m * 16 + fr, ks * 4 + ch);
        if (tk + 1 < NKT) STAGE_HALF(&Bs[nbuf][1][0], Bg1, tk + 1);
        __builtin_amdgcn_s_barrier();
        asm volatile("s_waitcnt lgkmcnt(0)" ::: "memory");
        __builtin_amdgcn_sched_barrier(0);
        __builtin_amdgcn_s_setprio(1);
        #pragma unroll
        for (int m = 0; m < 4; ++m)
            #pragma unroll
            for (int n = 0; n < 2; ++n)
                #pragma unroll
                for (int ks = 0; ks < 2; ++ks)
                    acc[4 + m][n] = __builtin_amdgcn_mfma_f32_16x16x32_f16(
                        afh[m][ks], bfa[n][ks], acc[4 + m][n], 0, 0, 0);
        __builtin_amdgcn_s_setprio(0);
        __builtin_amdgcn_s_barrier();
        __builtin_amdgcn_sched_barrier(0);

        // ---- phase 3: stage A-half0(t+2) into As[buf][0] (dead since p2) ----
        if (tk + 2 < NKT) STAGE_HALF(&As[buf][0][0], Ag0, tk + 2);
        __builtin_amdgcn_s_barrier();
        asm volatile("s_waitcnt lgkmcnt(0)" ::: "memory");
        __builtin_amdgcn_sched_barrier(0);
        __builtin_amdgcn_s_setprio(1);
        #pragma unroll
        for (int m = 0; m < 4; ++m)
            #pragma unroll
            for (int n = 0; n < 2; ++n)
                #pragma unroll
                for (int ks = 0; ks < 2; ++ks)
                    acc[4 + m][2 + n] = __builtin_amdgcn_mfma_f32_16x16x32_f16(
                        afh[m][ks], bfb[n][ks], acc[4 + m][2 + n], 0, 0, 0);
        __builtin_amdgcn_s_setprio(0);
        // boundary: tile t+1 ready when only A0(t+2)'s 2 loads remain in flight
        if (tk + 1 < NKT) {
            if (tk + 2 < NKT) asm volatile("s_waitcnt vmcnt(2)" ::: "memory");
            else              asm volatile("s_waitcnt vmcnt(0)" ::: "memory");
            __builtin_amdgcn_s_barrier();
            __builtin_amdgcn_sched_barrier(0);
        }
    }
    #undef STAGE_HALF

    // ---- epilogue: shfl-free. row = m0+wm*128+mf*16+(lane>>4)*4+r ;
    //      j = j0 + wn*32 + nf*16 + (lane&15). All 64 lanes store. ----
    const int colf = lane & 15;
    const int rowf = (lane >> 4) * 4;
    #pragma unroll
    for (int mf = 0; mf < 8; ++mf) {
        #pragma unroll
        for (int nf = 0; nf < 2; ++nf) {
            const int j = j0 + wn * 32 + nf * 16 + colf;
            #pragma unroll
            for (int r = 0; r < 4; ++r) {
                const int row = m0 + wm * 128 + mf * 16 + rowf + r;
                float re = acc[mf][nf][r];
                float im = acc[mf][2 + nf][r];
                float p = fminf((re * re + im * im) * invs[row], 1.0f);
                out[(size_t)row * DIM + j] = p;
            }
        }
    }
}

extern "C" void kernel_launch(void* const* d_in, const int* in_sizes, int n_in,
                              void* d_out, int out_size, void* d_ws, size_t ws_size,
                              hipStream_t stream) {
    const float* x = (const float*)d_in[0];     // (8192,1,32,32) fp32
    const float* w = (const float*)d_in[1];     // (16,10,3) fp32
    float* out = (float*)d_out;                 // (8192,1,32,32) fp32

    char* ws = (char*)d_ws;
    float*     gates = (float*)(ws + WS_GATES);
    int*       iperm = (int*)(ws + WS_IPERM);
    float*     invs  = (float*)(ws + WS_INVS);
    _Float16*  Xh    = (_Float16*)(ws + WS_XH);
    _Float16*  Bil   = (_Float16*)(ws + WS_BIL);
    // Ucol scratch lives in d_out (4 MB of its 32 MB); consumed by transpose
    // before gemm overwrites every element of d_out.
    _Float16*  Ucol  = (_Float16*)d_out;

    prep_kernel<<<1, 1024, 0, stream>>>(w, gates, iperm);
    fused_sim_kernel<<<3072, 256, 0, stream>>>(gates, iperm, Ucol, x, Xh, invs);
    transpose_kernel<<<dim3(32, 16), 256, 0, stream>>>(Ucol, Bil);
    gemm_kernel<<<256, 512, 0, stream>>>(Xh, Bil, invs, out);
}

// Round 18
// 95.031 us; speedup vs baseline: 1.6171x; 1.0037x over previous
//
#include <hip/hip_runtime.h>
#include <math.h>

#define NW     10
#define DIM    1024
#define QDEPTH 16

typedef __attribute__((ext_vector_type(8))) _Float16 f16x8;
typedef __attribute__((ext_vector_type(4))) _Float16 f16x4;
typedef __attribute__((ext_vector_type(2))) _Float16 f16x2;
typedef __attribute__((ext_vector_type(4))) float    f32x4;
typedef __attribute__((ext_vector_type(2))) float    f32x2;

// ---------------- ws layout ----------------
#define WS_GATES 0
#define WS_IPERM 8192
#define WS_INVS  81920
#define WS_XH    (1u << 20)     // 16 MB
#define WS_BIL   (17u << 20)    // 4 MB  (rows 0..1023 = Re U, 1024..2047 = Im U)
// d_out scratch: Ucol @0 (4 MB), consumed by transpose before gemm overwrites.

// slot hash: strictly increasing => bijective; max 1023+63+3 = 1089 < DIM+72.
#define SLOT(i) ((i) + ((i) >> 4) + ((i) >> 8))
#define STDIM   (DIM + 72)

// raw barrier: LDS writes drained before signaling, but VMEM loads stay in
// flight (unlike __syncthreads' vmcnt(0) drain). sched_barrier pins ordering.
#define SIM_BARRIER()                                             \
    do {                                                          \
        asm volatile("s_waitcnt lgkmcnt(0)" ::: "memory");        \
        __builtin_amdgcn_s_barrier();                             \
        __builtin_amdgcn_sched_barrier(0);                        \
    } while (0)

// Packed complex gate: f32x2 elementwise FMAs lower to v_pk_fma_f32.
__device__ __forceinline__ void gate2(const float* __restrict__ g, f32x2& p0, f32x2& p1) {
    f32x2 s0; s0.x = -p0.y; s0.y = p0.x;   // i*p0
    f32x2 s1; s1.x = -p1.y; s1.y = p1.x;   // i*p1
    f32x2 n0 = g[0]*p0 + g[1]*s0 + g[2]*p1 + g[3]*s1;
    f32x2 n1 = g[4]*p0 + g[5]*s0 + g[6]*p1 + g[7]*s1;
    p0 = n0; p1 = n1;
}

__global__ __launch_bounds__(1024)
void prep_kernel(const float* __restrict__ w, float* __restrict__ gates,
                 int* __restrict__ iperm) {
    int t = threadIdx.x;
    const float PI = 3.14159265358979323846f;
    if (t < QDEPTH * NW) {
        // Rot(phi,theta,omega) = RZ(omega) RY(theta) RZ(phi); angles = tanh(w)*pi
        float phi   = tanhf(w[t*3 + 0]) * PI;
        float theta = tanhf(w[t*3 + 1]) * PI;
        float omega = tanhf(w[t*3 + 2]) * PI;
        float ch = cosf(theta * 0.5f), sh = sinf(theta * 0.5f);
        float ap = (phi + omega) * 0.5f;
        float am = (phi - omega) * 0.5f;
        float* g = gates + t * 8;
        g[0] =  cosf(ap) * ch;  g[1] = -sinf(ap) * ch;   // m00
        g[2] = -cosf(am) * sh;  g[3] = -sinf(am) * sh;   // m01
        g[4] =  cosf(am) * sh;  g[5] = -sinf(am) * sh;   // m10
        g[6] =  cosf(ap) * ch;  g[7] =  sinf(ap) * ch;   // m11
    }
    // Forward CNOT-block gather, PRE-SLOTTED: iperm[l][v] = SLOT(G_l(v)).
    int v = t;
    for (int l = 0; l < QDEPTH; ++l) {
        int r = (l % (NW - 1)) + 1;
        int u = v;
        for (int wq = NW - 1; wq >= 0; --wq) {
            int bc = 9 - wq;
            int bt = 9 - ((wq + r) % NW);
            u ^= ((u >> bc) & 1) << bt;
        }
        iperm[l * DIM + v] = SLOT(u);
    }
}

// Fused: 3072 blocks.
//   bid < 1024        : 16-layer column sim -> Ucol row bid
//   bid in [1024,3072): normcast for batch rows 4*(bid-1024)..+3
// Ping-pong state; 2 raw barriers/layer (no vmcnt drain -> iperm prefetch
// stays in flight a full layer). Quad passes wave-local: DS ops of one wave
// are processed in order by the LDS unit, so the cross-lane write->read
// exchange needs no runtime waitcnt; sched_barrier(0) pins compiler order.
// Conflict-free lane->quad maps (derived per pass, per 32-lane phase):
// pp=3,2,0 canonical; pp=1 remapped (bits[7:4]=l&15, bits[1:0]=l>>4).
__global__ __launch_bounds__(256)
void fused_sim_kernel(const float* __restrict__ gates, const int* __restrict__ iperm,
                      _Float16* __restrict__ Ucol,
                      const float* __restrict__ x, _Float16* __restrict__ Xh,
                      float* __restrict__ invs) {
    __shared__ f32x2 st[2][STDIM];
    const int bid = blockIdx.x;
    const int t   = threadIdx.x;

    if (bid >= 1024) {
        // ---------------- normcast: 4 rows per block, 1 wave per row --------
        const int b = (bid - 1024) * 4 + (t >> 6);
        const int l = t & 63;
        const float4* xr = (const float4*)(x + (size_t)b * DIM);
        float4 v[4];
        float ss = 0.f;
        #pragma unroll
        for (int c = 0; c < 4; ++c) {
            v[c] = xr[l + c * 64];
            ss += v[c].x*v[c].x + v[c].y*v[c].y + v[c].z*v[c].z + v[c].w*v[c].w;
        }
        #pragma unroll
        for (int o = 32; o >= 1; o >>= 1) ss += __shfl_down(ss, o, 64);
        ss = __shfl(ss, 0, 64);
        if (l == 0) invs[b] = 1024.0f / ss;
        f16x4* xo = (f16x4*)(Xh + (size_t)b * DIM);
        #pragma unroll
        for (int c = 0; c < 4; ++c) {
            f16x4 h;
            h[0] = (_Float16)v[c].x; h[1] = (_Float16)v[c].y;
            h[2] = (_Float16)v[c].z; h[3] = (_Float16)v[c].w;
            xo[l + c * 64] = h;
        }
        return;
    }

    // ---------------- 16-layer column sim ----------------
    const int v = bid;
    const int w = t >> 6, l6 = t & 63;

    int s4[4];
    #pragma unroll
    for (int k = 0; k < 4; ++k) s4[k] = SLOT(t + k * 256);
    int sq[4][4];
    #pragma unroll
    for (int pp = 0; pp < 4; ++pp) {
        const int b = 2 * pp;
        int i00;
        if (pp == 1) {
            // conflict-free remap: bits[7:4]=l&15, bits[1:0]=l>>4
            i00 = (w << 8) | ((l6 & 15) << 4) | (l6 >> 4);
        } else {
            const int low = t & ((1 << b) - 1);
            i00 = ((t >> b) << (b + 2)) | low;
        }
        sq[pp][0] = SLOT(i00);
        sq[pp][1] = SLOT(i00 | (1 << b));
        sq[pp][2] = SLOT(i00 | (2 << b));
        sq[pp][3] = SLOT(i00 | (3 << b));
    }

    #pragma unroll
    for (int k = 0; k < 4; ++k) {
        int i = t + k * 256;
        f32x2 e; e.x = (i == v) ? 1.f : 0.f; e.y = 0.f;
        st[0][s4[k]] = e;
    }
    SIM_BARRIER();

    // pre-slotted perm indices for the NEXT layer's gather (prefetched)
    int pg0 = 0, pg1 = 0, pg2 = 0, pg3 = 0;
    int p = 0;   // state lives in st[p] (canonical layout)

    for (int l = 0; l < QDEPTH; ++l) {
        const float* gl = gates + l * NW * 8;
        const f32x2* src = st[p];
        f32x2*       dst = st[p ^ 1];

        // ---- barrier: all waves' quad writes to st[p] visible (l>0).
        if (l) SIM_BARRIER();

        // ---- b=8 session (wires 0,1): gather perm l-1 from src ----
        f32x2 a00, a01, a10, a11;
        if (l == 0) {
            a00 = src[s4[0]]; a01 = src[s4[1]]; a10 = src[s4[2]]; a11 = src[s4[3]];
        } else {
            a00 = src[pg0]; a01 = src[pg1]; a10 = src[pg2]; a11 = src[pg3];
        }
        // prefetch pre-slotted perm row l (used at layer l+1 / final output);
        // raw barriers keep these in flight across the layer boundary.
        {
            const int* ipn = iperm + l * DIM;
            pg0 = ipn[t]; pg1 = ipn[t + 256]; pg2 = ipn[t + 512]; pg3 = ipn[t + 768];
        }
        gate2(gl + 0, a00, a10);   // wire 0 (bit 9)
        gate2(gl + 0, a01, a11);
        gate2(gl + 8, a00, a01);   // wire 1 (bit 8)
        gate2(gl + 8, a10, a11);
        // write canonical into dst: no WAR with src reads -> no barrier here
        dst[s4[0]] = a00; dst[s4[1]] = a01; dst[s4[2]] = a10; dst[s4[3]] = a11;
        SIM_BARRIER();             // cross-wave canonical scatter visible

        // ---- quad passes b = 6,4,2,0 in dst: wave-local ----
        // Same-wave DS ops process in order -> no runtime wait between
        // passes; sched_barrier(0) prevents compiler reordering only.
        #pragma unroll
        for (int pp = 3; pp >= 0; --pp) {
            const int b = 2 * pp;
            const float* gh = gl + (8 - b) * 8;   // gate on bit b+1 (wire 8-b)
            const float* gm = gl + (9 - b) * 8;   // gate on bit b   (wire 9-b)
            f32x2 c00 = dst[sq[pp][0]], c01 = dst[sq[pp][1]];
            f32x2 c10 = dst[sq[pp][2]], c11 = dst[sq[pp][3]];
            gate2(gh, c00, c10);
            gate2(gh, c01, c11);
            gate2(gm, c00, c01);
            gate2(gm, c10, c11);
            dst[sq[pp][0]] = c00; dst[sq[pp][1]] = c01;
            dst[sq[pp][2]] = c10; dst[sq[pp][3]] = c11;
            __builtin_amdgcn_sched_barrier(0);
        }
        p ^= 1;   // state now in st[p]
    }

    // ---- output with fused final perm (pre-slotted row 15 in pg*) ----
    SIM_BARRIER();   // all waves' last quad writes visible
    const f32x2* fin = st[p];
    _Float16* col = Ucol + (size_t)v * 2048;
    {
        f32x2 a0 = fin[pg0], a1 = fin[pg1], a2 = fin[pg2], a3 = fin[pg3];
        f16x2 p0, p1, p2, p3;
        p0[0] = (_Float16)a0.x; p0[1] = (_Float16)a0.y;
        p1[0] = (_Float16)a1.x; p1[1] = (_Float16)a1.y;
        p2[0] = (_Float16)a2.x; p2[1] = (_Float16)a2.y;
        p3[0] = (_Float16)a3.x; p3[1] = (_Float16)a3.y;
        *(f16x2*)(col + 2 * t)         = p0;
        *(f16x2*)(col + 2 * (t + 256)) = p1;
        *(f16x2*)(col + 2 * (t + 512)) = p2;
        *(f16x2*)(col + 2 * (t + 768)) = p3;
    }
}

// Split-layout transpose: Bil[j][k] = Ucol[k][2j] (Re), Bil[1024+j][k] = Ucol[k][2j+1].
__global__ __launch_bounds__(256)
void transpose_kernel(const _Float16* __restrict__ Ucol, _Float16* __restrict__ Bil) {
    __shared__ _Float16 tile[64][72];
    const int bx = blockIdx.x;          // c-tile: 64 cols of Ucol = 32 j x {Re,Im}
    const int by = blockIdx.y;          // k-tile: 64 rows of Ucol
    const int t  = threadIdx.x;
    const int r  = t >> 3;              // 0..31
    const int c8 = (t & 7) * 8;         // 0..56

    #pragma unroll
    for (int kk = 0; kk < 64; kk += 32) {
        *(f16x8*)&tile[kk + r][c8] =
            *(const f16x8*)(Ucol + (size_t)(by * 64 + kk + r) * 2048 + bx * 64 + c8);
    }
    __syncthreads();
    {
        f16x8 ore, oim;
        #pragma unroll
        for (int u = 0; u < 8; ++u) {
            ore[u] = tile[c8 + u][2 * r];
            oim[u] = tile[c8 + u][2 * r + 1];
        }
        const int j = bx * 32 + r;
        *(f16x8*)(Bil + (size_t)j * 1024 + by * 64 + c8) = ore;
        *(f16x8*)(Bil + (size_t)(1024 + j) * 1024 + by * 64 + c8) = oim;
    }
}

// f16x8 frag read from a [rows][64] half-slot with chunk-XOR swizzle
__device__ __forceinline__ f16x8 ldsfrag(const _Float16* base, int hrow, int c) {
    return *(const f16x8*)(base + hrow * 64 + ((c ^ (hrow & 7)) << 3));
}

// ---------------- Main GEMM: 256-row x 128-j tile, BK=64, 8-phase ----------
// A = Xh (8192x1024). B = Bil split layout: Re rows [j0,j0+128),
// Im rows [1024+j0, 1024+j0+128). Each wave: 128 A-rows x 32 j, holding
// matched Re/Im accumulator pairs -> shfl-free coalesced epilogue.
#define NKT 16     // 1024 / 64

__global__ __launch_bounds__(512, 2)
void gemm_kernel(const _Float16* __restrict__ A, const _Float16* __restrict__ B,
                 const float* __restrict__ invs, float* __restrict__ out) {
    __shared__ _Float16 As[2][2][8192];   // [buf][M-half][128 rows x 64 k], 64 KB
    __shared__ _Float16 Bs[2][2][8192];   // [buf][Re/Im][128 rows x 64 k], 64 KB
    const int t    = threadIdx.x;
    const int lane = t & 63;
    const int wid  = t >> 6;      // 0..7
    const int wm   = wid >> 2;    // 0..1 : M-half (128 rows)
    const int wn   = wid & 3;     // 0..3 : j-slice (32 j)

    // T1: XCD x gets m-panels 4x..4x+3, all 8 j-panels
    const int bid   = blockIdx.x;          // 256 blocks
    const int local = bid >> 3;            // 0..31
    const int m0 = ((bid & 7) * 4 + (local & 3)) * 256;
    const int j0 = (local >> 2) * 128;     // 8 j-panels of 128

    const _Float16* Ag0 = A + (size_t)m0 * 1024;            // A rows m0..+127
    const _Float16* Ag1 = A + (size_t)(m0 + 128) * 1024;    // A rows +128..+255
    const _Float16* Bg0 = B + (size_t)j0 * 1024;            // Re rows j0..+127
    const _Float16* Bg1 = B + (size_t)(1024 + j0) * 1024;   // Im rows

    const int srow = t >> 3;                       // 0..63 (and +64)
    const int sgc  = ((t & 7) ^ (srow & 7)) * 8;   // swizzled source chunk, elems
    #define STAGE_HALF(dst, gbase, kt)                                              \
        do {                                                                        \
            __builtin_amdgcn_global_load_lds(                                       \
                (const __attribute__((address_space(1))) void*)                     \
                    ((gbase) + (size_t)srow * 1024 + (kt) * 64 + sgc),              \
                (__attribute__((address_space(3))) void*)((dst) + t * 8), 16, 0, 0);\
            __builtin_amdgcn_global_load_lds(                                       \
                (const __attribute__((address_space(1))) void*)                     \
                    ((gbase) + (size_t)(64 + srow) * 1024 + (kt) * 64 + sgc),       \
                (__attribute__((address_space(3))) void*)((dst) + 4096 + t * 8),    \
                16, 0, 0);                                                          \
        } while (0)

    // acc[mf][0..1] = Re j-tiles, acc[mf][2..3] = Im j-tiles (same j-slice)
    f32x4 acc[8][4];
    const f32x4 zero = {0.f, 0.f, 0.f, 0.f};
    #pragma unroll
    for (int i = 0; i < 8; ++i)
        #pragma unroll
        for (int j = 0; j < 4; ++j) acc[i][j] = zero;

    const int fr = lane & 15;       // frag row within 16
    const int ch = lane >> 4;       // 16B chunk within 32-k sub-tile
    const int brow = wn * 32;       // wave's B-row base (within each half)

    // ---- prologue: tile 0 fully + A-half0 of tile 1; wait tile 0 only ----
    STAGE_HALF(&As[0][0][0], Ag0, 0);
    STAGE_HALF(&As[0][1][0], Ag1, 0);
    STAGE_HALF(&Bs[0][0][0], Bg0, 0);
    STAGE_HALF(&Bs[0][1][0], Bg1, 0);
    STAGE_HALF(&As[1][0][0], Ag0, 1);
    asm volatile("s_waitcnt vmcnt(2)" ::: "memory");
    __builtin_amdgcn_s_barrier();
    __builtin_amdgcn_sched_barrier(0);

    for (int tk = 0; tk < NKT; ++tk) {
        const int buf = tk & 1, nbuf = buf ^ 1;
        const _Float16* Ab   = &As[buf][wm][0];
        const _Float16* BbRe = &Bs[buf][0][0];
        const _Float16* BbIm = &Bs[buf][1][0];

        f16x8 afl[4][2], afh[4][2], bfa[2][2], bfb[2][2];

        // ---- phase 0: read afl + bfa(Re); stage A-half1(t+1) ----
        #pragma unroll
        for (int m = 0; m < 4; ++m)
            #pragma unroll
            for (int ks = 0; ks < 2; ++ks)
                afl[m][ks] = ldsfrag(Ab, m * 16 + fr, ks * 4 + ch);
        #pragma unroll
        for (int n = 0; n < 2; ++n)
            #pragma unroll
            for (int ks = 0; ks < 2; ++ks)
                bfa[n][ks] = ldsfrag(BbRe, brow + n * 16 + fr, ks * 4 + ch);
        if (tk + 1 < NKT) STAGE_HALF(&As[nbuf][1][0], Ag1, tk + 1);
        __builtin_amdgcn_s_barrier();
        asm volatile("s_waitcnt lgkmcnt(0)" ::: "memory");
        __builtin_amdgcn_sched_barrier(0);
        __builtin_amdgcn_s_setprio(1);
        #pragma unroll
        for (int m = 0; m < 4; ++m)
            #pragma unroll
            for (int n = 0; n < 2; ++n)
                #pragma unroll
                for (int ks = 0; ks < 2; ++ks)
                    acc[m][n] = __builtin_amdgcn_mfma_f32_16x16x32_f16(
                        afl[m][ks], bfa[n][ks], acc[m][n], 0, 0, 0);
        __builtin_amdgcn_s_setprio(0);
        __builtin_amdgcn_s_barrier();
        __builtin_amdgcn_sched_barrier(0);

        // ---- phase 1: read bfb(Im); stage B-Re(t+1) ----
        #pragma unroll
        for (int n = 0; n < 2; ++n)
            #pragma unroll
            for (int ks = 0; ks < 2; ++ks)
                bfb[n][ks] = ldsfrag(BbIm, brow + n * 16 + fr, ks * 4 + ch);
        if (tk + 1 < NKT) STAGE_HALF(&Bs[nbuf][0][0], Bg0, tk + 1);
        __builtin_amdgcn_s_barrier();
        asm volatile("s_waitcnt lgkmcnt(0)" ::: "memory");
        __builtin_amdgcn_sched_barrier(0);
        __builtin_amdgcn_s_setprio(1);
        #pragma unroll
        for (int m = 0; m < 4; ++m)
            #pragma unroll
            for (int n = 0; n < 2; ++n)
                #pragma unroll
                for (int ks = 0; ks < 2; ++ks)
                    acc[m][2 + n] = __builtin_amdgcn_mfma_f32_16x16x32_f16(
                        afl[m][ks], bfb[n][ks], acc[m][2 + n], 0, 0, 0);
        __builtin_amdgcn_s_setprio(0);
        __builtin_amdgcn_s_barrier();
        __builtin_amdgcn_sched_barrier(0);

        // ---- phase 2: read afh; stage B-Im(t+1) ----
        #pragma unroll
        for (int m = 0; m < 4; ++m)
            #pragma unroll
            for (int ks = 0; ks < 2; ++ks)
                afh[m][ks] = ldsfrag(Ab, 64 + m * 16 + fr, ks * 4 + ch);
        if (tk + 1 < NKT) STAGE_HALF(&Bs[nbuf][1][0], Bg1, tk + 1);
        __builtin_amdgcn_s_barrier();
        asm volatile("s_waitcnt lgkmcnt(0)" ::: "memory");
        __builtin_amdgcn_sched_barrier(0);
        __builtin_amdgcn_s_setprio(1);
        #pragma unroll
        for (int m = 0; m < 4; ++m)
            #pragma unroll
            for (int n = 0; n < 2; ++n)
                #pragma unroll
                for (int ks = 0; ks < 2; ++ks)
                    acc[4 + m][n] = __builtin_amdgcn_mfma_f32_16x16x32_f16(
                        afh[m][ks], bfa[n][ks], acc[4 + m][n], 0, 0, 0);
        __builtin_amdgcn_s_setprio(0);
        __builtin_amdgcn_s_barrier();
        __builtin_amdgcn_sched_barrier(0);

        // ---- phase 3: stage A-half0(t+2) into As[buf][0] (dead since p2) ----
        if (tk + 2 < NKT) STAGE_HALF(&As[buf][0][0], Ag0, tk + 2);
        __builtin_amdgcn_s_barrier();
        asm volatile("s_waitcnt lgkmcnt(0)" ::: "memory");
        __builtin_amdgcn_sched_barrier(0);
        __builtin_amdgcn_s_setprio(1);
        #pragma unroll
        for (int m = 0; m < 4; ++m)
            #pragma unroll
            for (int n = 0; n < 2; ++n)
                #pragma unroll
                for (int ks = 0; ks < 2; ++ks)
                    acc[4 + m][2 + n] = __builtin_amdgcn_mfma_f32_16x16x32_f16(
                        afh[m][ks], bfb[n][ks], acc[4 + m][2 + n], 0, 0, 0);
        __builtin_amdgcn_s_setprio(0);
        // boundary: tile t+1 ready when only A0(t+2)'s 2 loads remain in flight
        if (tk + 1 < NKT) {
            if (tk + 2 < NKT) asm volatile("s_waitcnt vmcnt(2)" ::: "memory");
            else              asm volatile("s_waitcnt vmcnt(0)" ::: "memory");
            __builtin_amdgcn_s_barrier();
            __builtin_amdgcn_sched_barrier(0);
        }
    }
    #undef STAGE_HALF

    // ---- epilogue: shfl-free. row = m0+wm*128+mf*16+(lane>>4)*4+r ;
    //      j = j0 + wn*32 + nf*16 + (lane&15). All 64 lanes store. ----
    const int colf = lane & 15;
    const int rowf = (lane >> 4) * 4;
    #pragma unroll
    for (int mf = 0; mf < 8; ++mf) {
        #pragma unroll
        for (int nf = 0; nf < 2; ++nf) {
            const int j = j0 + wn * 32 + nf * 16 + colf;
            #pragma unroll
            for (int r = 0; r < 4; ++r) {
                const int row = m0 + wm * 128 + mf * 16 + rowf + r;
                float re = acc[mf][nf][r];
                float im = acc[mf][2 + nf][r];
                float p = fminf((re * re + im * im) * invs[row], 1.0f);
                out[(size_t)row * DIM + j] = p;
            }
        }
    }
}

extern "C" void kernel_launch(void* const* d_in, const int* in_sizes, int n_in,
                              void* d_out, int out_size, void* d_ws, size_t ws_size,
                              hipStream_t stream) {
    const float* x = (const float*)d_in[0];     // (8192,1,32,32) fp32
    const float* w = (const float*)d_in[1];     // (16,10,3) fp32
    float* out = (float*)d_out;                 // (8192,1,32,32) fp32

    char* ws = (char*)d_ws;
    float*     gates = (float*)(ws + WS_GATES);
    int*       iperm = (int*)(ws + WS_IPERM);
    float*     invs  = (float*)(ws + WS_INVS);
    _Float16*  Xh    = (_Float16*)(ws + WS_XH);
    _Float16*  Bil   = (_Float16*)(ws + WS_BIL);
    // Ucol scratch lives in d_out (4 MB of its 32 MB); consumed by transpose
    // before gemm overwrites every element of d_out.
    _Float16*  Ucol  = (_Float16*)d_out;

    prep_kernel<<<1, 1024, 0, stream>>>(w, gates, iperm);
    fused_sim_kernel<<<3072, 256, 0, stream>>>(gates, iperm, Ucol, x, Xh, invs);
    transpose_kernel<<<dim3(32, 16), 256, 0, stream>>>(Ucol, Bil);
    gemm_kernel<<<256, 512, 0, stream>>>(Xh, Bil, invs, out);
}